// Round 3
// baseline (272.525 us; speedup 1.0000x reference)
//
#include <hip/hip_runtime.h>
#include <hip/hip_bf16.h>

#define BB 4
#define CC 256
#define CHH 128
#define NN 4096
#define KSHIFT 12.0f

typedef __attribute__((ext_vector_type(8))) short bf16x8;
typedef __attribute__((ext_vector_type(4))) float f32x4;

__device__ __forceinline__ float to_f(float v) { return v; }
__device__ __forceinline__ float to_f(__hip_bfloat16 v) { return __bfloat162float(v); }
__device__ __forceinline__ void st_f(float* p, float v) { *p = v; }
__device__ __forceinline__ void st_f(__hip_bfloat16* p, float v) { *p = __float2bfloat16(v); }
__device__ __forceinline__ unsigned short f2bf(float f) {
    __hip_bfloat16 h = __float2bfloat16(f);
    unsigned short u;
    __builtin_memcpy(&u, &h, 2);
    return u;
}
__device__ __forceinline__ bf16x8 ldb8(const unsigned short* p) { return *(const bf16x8*)p; }

// async global->LDS, 16 B per lane. LDS dest = wave-uniform base + lane*16.
__device__ __forceinline__ void gload_lds16(const unsigned short* g, unsigned short* l) {
    __builtin_amdgcn_global_load_lds(
        (const __attribute__((address_space(1))) unsigned int*)g,
        (__attribute__((address_space(3))) unsigned int*)l, 16, 0, 0);
}

// ---------------------------------------------------------------------------
// Kernel 0: wire-dtype detection (proven rounds 3-10 — keep).
// ---------------------------------------------------------------------------
__global__ void detect_kernel(const void* __restrict__ tb, int* __restrict__ flag) {
    if (threadIdx.x == 0) {
        const __hip_bfloat16* p = (const __hip_bfloat16*)tb;
        int big = 0, zeros = 0;
        for (int i = 0; i < 128; ++i) {
            float v = __bfloat162float(p[i]);
            if (!(fabsf(v) <= 0.5f)) big = 1;
            if ((i & 1) == 0 && v == 0.0f) zeros++;
        }
        *flag = (big || zeros >= 32) ? 1 : 0;
    }
}

// ---------------------------------------------------------------------------
// Kernel 1: convert all weights/biases once (proven round 6).
// ---------------------------------------------------------------------------
template <typename T>
__device__ __forceinline__ void prep_body(const T* tw, const T* fw, const T* gw, const T* ow,
                                          const T* tb2, const T* fb, const T* gb, const T* ob,
                                          unsigned short* Wb, unsigned short* OWb,
                                          float* Bf, float* OBf) {
    int idx = blockIdx.x * 256 + threadIdx.x;
    if (idx < 98304) {
        int cv = idx >> 15, rem = idx & 32767;
        const T* src = cv == 0 ? tw : (cv == 1 ? fw : gw);
        Wb[idx] = f2bf(to_f(src[rem]));
    } else if (idx < 131072) {
        OWb[idx - 98304] = f2bf(to_f(ow[idx - 98304]));
    } else if (idx < 131456) {
        int r = idx - 131072;
        int cv = r >> 7, j = r & 127;
        const T* src = cv == 0 ? tb2 : (cv == 1 ? fb : gb);
        Bf[r] = to_f(src[j]);
    } else if (idx < 131712) {
        OBf[idx - 131456] = to_f(ob[idx - 131456]);
    }
}

__global__ void prep_kernel(const void* tw, const void* fw, const void* gw, const void* ow,
                            const void* tb2, const void* fb, const void* gb, const void* ob,
                            const int* __restrict__ flag,
                            unsigned short* Wb, unsigned short* OWb, float* Bf, float* OBf) {
    if (*flag)
        prep_body<float>((const float*)tw, (const float*)fw, (const float*)gw, (const float*)ow,
                         (const float*)tb2, (const float*)fb, (const float*)gb, (const float*)ob,
                         Wb, OWb, Bf, OBf);
    else
        prep_body<__hip_bfloat16>((const __hip_bfloat16*)tw, (const __hip_bfloat16*)fw,
                                  (const __hip_bfloat16*)gw, (const __hip_bfloat16*)ow,
                                  (const __hip_bfloat16*)tb2, (const __hip_bfloat16*)fb,
                                  (const __hip_bfloat16*)gb, (const __hip_bfloat16*)ob,
                                  Wb, OWb, Bf, OBf);
}

// ---------------------------------------------------------------------------
// Kernel 2: xt[b][p][c] = bf16(x[b][c][p]) (proven round 6).
// ---------------------------------------------------------------------------
template <typename T>
__device__ __forceinline__ void xtrans_body(const T* __restrict__ x, unsigned short* __restrict__ xt) {
    int b = blockIdx.z;
    const T* in = x + (size_t)b * CC * NN;
    unsigned short* out = xt + (size_t)b * NN * CC;
    int p0 = blockIdx.x * 64, c0 = blockIdx.y * 64;
    __shared__ unsigned short t[64][68];
    int flat = threadIdx.x;
#pragma unroll
    for (int tt = 0; tt < 16; ++tt) {
        int id = flat + tt * 256;
        int rr = id >> 6, cc = id & 63;
        t[cc][rr] = f2bf(to_f(in[(size_t)(c0 + rr) * NN + p0 + cc]));
    }
    __syncthreads();
#pragma unroll
    for (int tt = 0; tt < 16; ++tt) {
        int id = flat + tt * 256;
        int pp = id >> 6, jj = id & 63;
        out[(size_t)(p0 + pp) * CC + c0 + jj] = t[pp][jj];
    }
}

__launch_bounds__(256)
__global__ void xtrans_kernel(const void* x, const int* __restrict__ flag,
                              unsigned short* __restrict__ xt) {
    if (*flag) xtrans_body<float>((const float*)x, xt);
    else       xtrans_body<__hip_bfloat16>((const __hip_bfloat16*)x, xt);
}

// ---------------------------------------------------------------------------
// Kernel 3: three 1x1 convs via MFMA.
//   cv=0 (theta): natural (CH,N) store -> T1b (== (N,CH) view).
//   cv=1 (phi):   T2t[p*128+o] written directly via 16x16 in-wave shfl
//                 transpose (audited: lane l' pulls D[o0+(l'&3)*4+k][p0+l'>>2]).
//   cv=2 (g):     natural store -> T3b. X3t CANNOT be fused (round-11 bug);
//                 standalone transpose reinstated below.
// ---------------------------------------------------------------------------
__launch_bounds__(256)
__global__ void conv3_mfma_kernel(const unsigned short* __restrict__ xt,
                                  const unsigned short* __restrict__ Wb,
                                  const float* __restrict__ Bf,
                                  unsigned short* __restrict__ T1b,
                                  unsigned short* __restrict__ T2t,
                                  unsigned short* __restrict__ T3b) {
    int b = blockIdx.y;
    int p0 = blockIdx.x * 16;
    int flat = threadIdx.x;
    int w = flat >> 6, lane = flat & 63, m = lane & 15, quad = lane >> 4;
    const unsigned short* xrow = xt + ((size_t)b * NN + p0 + m) * CC;
    bf16x8 xf[8];
#pragma unroll
    for (int kc = 0; kc < 8; ++kc)
        xf[kc] = ldb8(&xrow[kc * 32 + quad * 8]);
    unsigned short* t1  = T1b + (size_t)b * CHH * NN;
    unsigned short* t2t = T2t + (size_t)b * CHH * NN;   // [p][o], row stride 128
    unsigned short* t3  = T3b + (size_t)b * CHH * NN;   // natural (CH,N)
#pragma unroll
    for (int q = 0; q < 6; ++q) {
        int t = w * 6 + q;
        int cv = t >> 3, ot = t & 7;
        int o0 = ot * 16;
        const unsigned short* wrow = Wb + ((size_t)cv * CHH + o0 + m) * CC;
        f32x4 acc = {0.f, 0.f, 0.f, 0.f};
#pragma unroll
        for (int kc = 0; kc < 8; ++kc) {
            bf16x8 wf = ldb8(&wrow[kc * 32 + quad * 8]);
            acc = __builtin_amdgcn_mfma_f32_16x16x32_bf16(wf, xf[kc], acc, 0, 0, 0);
        }
        unsigned short hv[4];
#pragma unroll
        for (int r = 0; r < 4; ++r)
            hv[r] = f2bf(acc[r] + Bf[cv * CHH + o0 + quad * 4 + r]);
        if (cv == 1) {
            unsigned int lo = (unsigned int)hv[0] | ((unsigned int)hv[1] << 16);
            unsigned int hi = (unsigned int)hv[2] | ((unsigned int)hv[3] << 16);
            int src = (lane & 3) * 16 + (lane >> 2);
            unsigned int tlo = (unsigned int)__shfl((int)lo, src, 64);
            unsigned int thi = (unsigned int)__shfl((int)hi, src, 64);
            unsigned int* dst = (unsigned int*)&t2t[(size_t)(p0 + (lane >> 2)) * CHH +
                                                    o0 + (lane & 3) * 4];
            dst[0] = tlo;
            dst[1] = thi;
        } else {
            unsigned short* outp = (cv == 0) ? t1 : t3;
#pragma unroll
            for (int r = 0; r < 4; ++r)
                outp[(size_t)(o0 + quad * 4 + r) * NN + p0 + m] = hv[r];
        }
    }
}

// ---------------------------------------------------------------------------
// Kernel 4: generic bf16 tiled transpose (proven) — X3t only.
// ---------------------------------------------------------------------------
__launch_bounds__(256)
__global__ void transpose_kernel(const unsigned short* __restrict__ in,
                                 unsigned short* __restrict__ out, int R, int C) {
    int bz = blockIdx.z;
    in  += (size_t)bz * R * C;
    out += (size_t)bz * R * C;
    int c0 = blockIdx.x * 64, r0 = blockIdx.y * 64;
    __shared__ unsigned short t[64][68];
    int flat = threadIdx.x;
#pragma unroll
    for (int tt = 0; tt < 16; ++tt) {
        int id = flat + tt * 256;
        int r = id >> 6, c = id & 63;
        t[c][r] = in[(size_t)(r0 + r) * C + c0 + c];
    }
    __syncthreads();
#pragma unroll
    for (int tt = 0; tt < 16; ++tt) {
        int id = flat + tt * 256;
        int c = id >> 6, r = id & 63;
        out[(size_t)(c0 + c) * R + r0 + r] = t[c][r];
    }
}

// ---------------------------------------------------------------------------
// Kernel 5 (pass A): colsum exp(S-K). Round 12 double-buffered theta tile +
// single barrier per tile. Grid 1024 (4 blocks/CU x 4 waves = 4 waves/SIMD),
// LDS 32 KB. Unchanged this round.
// ---------------------------------------------------------------------------
__launch_bounds__(256)
__global__ void stats_mfma_kernel(const unsigned short* __restrict__ T1b,
                                  const unsigned short* __restrict__ T2t,
                                  float* __restrict__ Lpart) {
    int blk = blockIdx.x;
    int b = (blk & 7) >> 1;
    int rest = (blk >> 3) * 2 + (blk & 1);   // 0..255 = strip*8 + iq
    int strip = rest >> 3, iq = rest & 7;
    int ibase = iq * 512;
    int flat = threadIdx.x;
    int w = flat >> 6, lane = flat & 63, m = lane & 15, quad = lane >> 4;
    const unsigned short* A  = T1b + (size_t)b * CHH * NN;
    const unsigned short* Bt = T2t + (size_t)b * CHH * NN;
    __shared__ unsigned short th[2][64 * 128];   // double-buffered theta tile

    int u0w = strip * 128 + w * 32;           // this wave's 32-u window
    bf16x8 bfr[2][4];
#pragma unroll
    for (int g = 0; g < 2; ++g)
#pragma unroll
        for (int kc = 0; kc < 4; ++kc)
            bfr[g][kc] = ldb8(&Bt[(size_t)(u0w + g * 16 + m) * CHH + kc * 32 + quad * 8]);

#define STAGE_TH(dst, ii)                                                          \
    _Pragma("unroll")                                                              \
    for (int i_ = 0; i_ < 4; ++i_) {                                               \
        int sl = i_ * 256 + flat;                                                  \
        int r_ = sl >> 4, ch_ = sl & 15;                                           \
        int c_ = ch_ ^ (r_ & 7);                                                   \
        gload_lds16(&A[(size_t)((ii) + r_) * CHH + c_ * 8], &th[dst][sl * 8]);     \
    }

    float csum[2] = {0.f, 0.f};
    STAGE_TH(0, ibase);                      // prologue: tile 0
    __syncthreads();                         // tile 0 ready (vmcnt drained)
    int cur = 0;
    for (int t = 0; t < 8; ++t) {            // 8 i-tiles of 64 in this chunk
        if (t < 7) { STAGE_TH(cur ^ 1, ibase + (t + 1) * 64); }
        const unsigned short* thc = th[cur];
#pragma unroll
        for (int s = 0; s < 4; ++s) {
            int irow = s * 16 + m;
            bf16x8 af[4];
#pragma unroll
            for (int kc = 0; kc < 4; ++kc) {
                int ch = (kc * 4 + quad) ^ (irow & 7);
                af[kc] = *(const bf16x8*)&thc[irow * 128 + ch * 8];
            }
#pragma unroll
            for (int g = 0; g < 2; ++g) {
                f32x4 acc = {0.f, 0.f, 0.f, 0.f};
#pragma unroll
                for (int kc = 0; kc < 4; ++kc)
                    acc = __builtin_amdgcn_mfma_f32_16x16x32_bf16(af[kc], bfr[g][kc], acc, 0, 0, 0);
#pragma unroll
                for (int r = 0; r < 4; ++r)
                    csum[g] += __expf(acc[r] - KSHIFT);
            }
        }
        if (t < 7) {
            __syncthreads();                 // publishes tile t+1, protects buf t
            cur ^= 1;
        }
    }
#undef STAGE_TH
#pragma unroll
    for (int g = 0; g < 2; ++g) {
        csum[g] += __shfl_xor(csum[g], 16, 64);
        csum[g] += __shfl_xor(csum[g], 32, 64);
        if (lane < 16)
            Lpart[((size_t)iq * BB + b) * NN + u0w + g * 16 + m] = csum[g];
    }
}

// ---------------------------------------------------------------------------
// Kernel 6 (pass B): Y = P @ X3. ROUND 14: 8 waves = 4 i-groups (32 rows
// each) x 2 u-halves of the 64-u tile. Restores round-1's 2-MFMAs-per-
// ds_read ratio (18 reads feed 32 MFMAs) at round-2's 4 waves/SIMD.
// LDS 72 KB arena: bt dbuf 32K + x3 single 16K + pT 20K + llh 4K ->
// 2 blocks/CU. x3 single-buffered: staged at tile bottom (after PV-read
// barrier), drained by the post-S barrier of the next tile. u-half wave
// pairs merge partial Y in f32 via an LDS epilogue (scratch reuses the
// dead arena) -> Yp semantics identical to round 2 (4 bf16 partials).
// ---------------------------------------------------------------------------
__launch_bounds__(512, 4)
__global__ void attn_mfma_kernel(const unsigned short* __restrict__ T1b,
                                 const unsigned short* __restrict__ T2t,
                                 const unsigned short* __restrict__ X3t,
                                 const float* __restrict__ Lpart,
                                 unsigned short* __restrict__ Yp0,
                                 unsigned short* __restrict__ Yp1,
                                 unsigned short* __restrict__ Yp2,
                                 unsigned short* __restrict__ Yp3) {
    int blk = blockIdx.x;
    int b = (blk & 7) >> 1;
    int rest = (blk >> 3) * 2 + (blk & 1);   // 0..127 = it*4 + uc
    int it = rest >> 2, uc = rest & 3;
    int i0 = it * 128;
    unsigned short* Yp = uc == 0 ? Yp0 : (uc == 1 ? Yp1 : (uc == 2 ? Yp2 : Yp3));
    int flat = threadIdx.x;                   // 0..511
    int w = flat >> 6, lane = flat & 63, m = lane & 15, quad = lane >> 4;
    int ig = w & 3, h = w >> 2;               // i-group (32 rows), u-half
    const unsigned short* A  = T1b + (size_t)b * CHH * NN;
    const unsigned short* Bt = T2t + (size_t)b * CHH * NN;
    const unsigned short* X3 = X3t + (size_t)b * CHH * NN;

    // LDS arena, 73,728 B total:
    //   [     0, 32768) bt   : phi^T tile, swizzled, dbuf 2 x 64x128 bf16
    //   [ 32768, 49152) x3   : X3 tile, swizzled, single 128x64 bf16
    //   [ 49152, 69632) pT   : wave-private P tiles [8][2][16][40] bf16
    //   [ 69632, 73728) llh  : 1024 f32 LL values
    // Epilogue merge scratch (4 x 32 x 132 f32 = 67,584 B) reuses [0, 67584).
    __shared__ __align__(16) unsigned char smem[73728];
    unsigned short* bt0 = (unsigned short*)smem;
    unsigned short* x3s = (unsigned short*)(smem + 32768);
    unsigned short* pTw = (unsigned short*)(smem + 49152) + w * 1280; // [2][16][40]
    float* llh = (float*)(smem + 69632);

    int ubeg = uc * 1024;
#pragma unroll
    for (int k = 0; k < 2; ++k) {             // LL prologue
        int idx = k * 512 + flat;
        int u = ubeg + idx;
        float s = 0.f;
#pragma unroll
        for (int c = 0; c < 8; ++c)
            s += Lpart[((size_t)c * BB + b) * NN + u];
        llh[idx] = logf(s) + KSHIFT;
    }

    int iw = i0 + ig * 32;                    // this wave's 32 i-rows
    bf16x8 ath[2][4];
#pragma unroll
    for (int g = 0; g < 2; ++g)
#pragma unroll
        for (int kc = 0; kc < 4; ++kc)
            ath[g][kc] = ldb8(&A[(size_t)(iw + g * 16 + m) * CHH + kc * 32 + quad * 8]);
    f32x4 yacc[2][8];
#pragma unroll
    for (int g = 0; g < 2; ++g)
#pragma unroll
        for (int js = 0; js < 8; ++js) yacc[g][js] = (f32x4){0.f, 0.f, 0.f, 0.f};

#define STAGE_BT(dst, uu)                                                          \
    _Pragma("unroll")                                                              \
    for (int i_ = 0; i_ < 2; ++i_) {          /* 16 KB */                          \
        int sl = i_ * 512 + flat;                                                  \
        int u_ = sl >> 4, ch_ = sl & 15;                                           \
        int c_ = ch_ ^ (u_ & 7);                                                   \
        gload_lds16(&Bt[(size_t)((uu) + u_) * CHH + c_ * 8],                       \
                    bt0 + (dst) * 8192 + sl * 8);                                  \
    }
#define STAGE_X3(uu)                                                               \
    _Pragma("unroll")                                                              \
    for (int i_ = 0; i_ < 2; ++i_) {          /* 16 KB */                          \
        int sl = i_ * 512 + flat;                                                  \
        int j_ = sl >> 3, ch_ = sl & 7;                                            \
        int c_ = ch_ ^ (j_ & 7);                                                   \
        gload_lds16(&X3[(size_t)j_ * NN + (uu) + c_ * 8], x3s + sl * 8);           \
    }

    STAGE_BT(0, ubeg);                        // prologue: bt tile 0 + x3 tile 0
    STAGE_X3(ubeg);
    __syncthreads();                          // staging drained + llh visible
    int cur = 0;
    for (int t = 0; t < 16; ++t) {
        int u0 = ubeg + t * 64;
        if (t < 15) { STAGE_BT(cur ^ 1, u0 + 64); }   // drains at barrier A
        const unsigned short* btc = bt0 + cur * 8192;
        // ---- S phase: S(32i x 32u-half), exp, P -> wave-private LDS ----
#pragma unroll
        for (int su = 0; su < 2; ++su) {
            int ul = h * 32 + su * 16 + m;    // u within tile (this wave's half)
            f32x4 a0 = {0.f, 0.f, 0.f, 0.f}, a1 = {0.f, 0.f, 0.f, 0.f};
#pragma unroll
            for (int kc = 0; kc < 4; ++kc) {
                int ch = (kc * 4 + quad) ^ (ul & 7);
                bf16x8 bf = *(const bf16x8*)&btc[ul * 128 + ch * 8];
                a0 = __builtin_amdgcn_mfma_f32_16x16x32_bf16(ath[0][kc], bf, a0, 0, 0, 0);
                a1 = __builtin_amdgcn_mfma_f32_16x16x32_bf16(ath[1][kc], bf, a1, 0, 0, 0);
            }
            float ll = llh[u0 - ubeg + ul];
#pragma unroll
            for (int r = 0; r < 4; ++r) {
                pTw[(quad * 4 + r) * 40 + su * 16 + m]       = f2bf(__expf(a0[r] - ll));
                pTw[640 + (quad * 4 + r) * 40 + su * 16 + m] = f2bf(__expf(a1[r] - ll));
            }
        }
        bf16x8 pa0 = *(const bf16x8*)&pTw[m * 40 + quad * 8];
        bf16x8 pa1 = *(const bf16x8*)&pTw[640 + m * 40 + quad * 8];
        __syncthreads();                      // A: x3(t) + bt(t+1) staging drained
        // ---- PV phase: Y(32i x 128j) += P_half @ X3_half ----
#pragma unroll
        for (int js = 0; js < 8; ++js) {
            int j = js * 16 + m;
            int ch = (h * 4 + quad) ^ (j & 7);
            bf16x8 xb = *(const bf16x8*)&x3s[j * 64 + ch * 8];
            yacc[0][js] = __builtin_amdgcn_mfma_f32_16x16x32_bf16(pa0, xb, yacc[0][js], 0, 0, 0);
            yacc[1][js] = __builtin_amdgcn_mfma_f32_16x16x32_bf16(pa1, xb, yacc[1][js], 0, 0, 0);
        }
        __syncthreads();                      // B: all PV(t) x3 reads done
        if (t < 15) { STAGE_X3(u0 + 64); }    // drains at A(t+1), under S(t+1)
        cur ^= 1;
    }
#undef STAGE_BT
#undef STAGE_X3
    // ---- epilogue: merge u-half partials (waves ig,h=1 -> ig,h=0) in f32 ----
    float* scr = (float*)smem;                // [4 ig][32 rows][132] f32, 67,584 B
    if (h == 1) {
#pragma unroll
        for (int g = 0; g < 2; ++g)
#pragma unroll
            for (int js = 0; js < 8; ++js)
#pragma unroll
                for (int r = 0; r < 4; ++r)
                    scr[ig * 4224 + (g * 16 + quad * 4 + r) * 132 + js * 16 + m] =
                        yacc[g][js][r];
    }
    __syncthreads();
    if (h == 0) {
#pragma unroll
        for (int g = 0; g < 2; ++g)
#pragma unroll
            for (int js = 0; js < 8; ++js)
#pragma unroll
                for (int r = 0; r < 4; ++r) {
                    float v = yacc[g][js][r] +
                              scr[ig * 4224 + (g * 16 + quad * 4 + r) * 132 + js * 16 + m];
                    Yp[((size_t)b * NN + iw + g * 16 + quad * 4 + r) * CHH + js * 16 + m] =
                        f2bf(v);
                }
    }
}

// ---------------------------------------------------------------------------
// Kernel 7: out = x + out_w @ (Yp0+Yp1+Yp2+Yp3)^T + out_b via MFMA
// (proven round 10; partials merged in the fp32 accumulator).
// ---------------------------------------------------------------------------
template <typename T>
__device__ __forceinline__ void outconv_body(const T* __restrict__ x,
                                             const unsigned short* __restrict__ Yp0,
                                             const unsigned short* __restrict__ Yp1,
                                             const unsigned short* __restrict__ Yp2,
                                             const unsigned short* __restrict__ Yp3,
                                             const unsigned short* __restrict__ OWb,
                                             const float* __restrict__ OBf,
                                             T* __restrict__ out) {
    int b = blockIdx.y;
    int p0 = blockIdx.x * 16;
    int flat = threadIdx.x;
    int w = flat >> 6, lane = flat & 63, m = lane & 15, quad = lane >> 4;
    size_t yoff = ((size_t)b * NN + p0 + m) * CHH;
    const unsigned short* yrows[4] = {Yp0 + yoff, Yp1 + yoff, Yp2 + yoff, Yp3 + yoff};
    bf16x8 yf[4][4];
#pragma unroll
    for (int pz = 0; pz < 4; ++pz)
#pragma unroll
        for (int kc = 0; kc < 4; ++kc)
            yf[pz][kc] = ldb8(&yrows[pz][kc * 32 + quad * 8]);
#pragma unroll
    for (int q = 0; q < 4; ++q) {
        int o0 = (w * 4 + q) * 16;
        const unsigned short* wrow = OWb + (size_t)(o0 + m) * CHH;
        f32x4 acc = {0.f, 0.f, 0.f, 0.f};
#pragma unroll
        for (int kc = 0; kc < 4; ++kc) {
            bf16x8 aw = ldb8(&wrow[kc * 32 + quad * 8]);
#pragma unroll
            for (int pz = 0; pz < 4; ++pz)
                acc = __builtin_amdgcn_mfma_f32_16x16x32_bf16(aw, yf[pz][kc], acc, 0, 0, 0);
        }
#pragma unroll
        for (int r = 0; r < 4; ++r) {
            int co = o0 + quad * 4 + r;
            size_t oi = ((size_t)b * CC + co) * NN + p0 + m;
            st_f(&out[oi], acc[r] + OBf[co] + to_f(x[oi]));
        }
    }
}

__launch_bounds__(256)
__global__ void outconv_mfma_kernel(const void* x,
                                    const unsigned short* __restrict__ Yp0,
                                    const unsigned short* __restrict__ Yp1,
                                    const unsigned short* __restrict__ Yp2,
                                    const unsigned short* __restrict__ Yp3,
                                    const unsigned short* __restrict__ OWb,
                                    const float* __restrict__ OBf,
                                    const int* __restrict__ flag, void* out) {
    if (*flag)
        outconv_body<float>((const float*)x, Yp0, Yp1, Yp2, Yp3, OWb, OBf, (float*)out);
    else
        outconv_body<__hip_bfloat16>((const __hip_bfloat16*)x, Yp0, Yp1, Yp2, Yp3, OWb, OBf,
                                     (__hip_bfloat16*)out);
}

extern "C" void kernel_launch(void* const* d_in, const int* in_sizes, int n_in,
                              void* d_out, int out_size, void* d_ws, size_t ws_size,
                              hipStream_t stream) {
    const void* x  = d_in[0];
    const void* tw = d_in[1];
    const void* tb = d_in[2];
    const void* fw = d_in[3];
    const void* fb = d_in[4];
    const void* gw = d_in[5];
    const void* gb = d_in[6];
    const void* ow = d_in[7];
    const void* ob = d_in[8];

    // Workspace (~30 MB): conv3 writes T1b natural, T2t fused-transposed,
    // T3b natural; transpose T3b -> X3t. Aliases: Yp0/Yp1 <- xt (dead after
    // conv3), Yp2 <- T3b (dead after the X3t transpose), Yp3 fresh.
    const size_t TE = (size_t)BB * CHH * NN;        // 2,097,152
    unsigned short* T1b = (unsigned short*)d_ws;
    unsigned short* T2t = T1b + TE;                 // phi transposed [p][o]
    unsigned short* X3t = T2t + TE;                 // g-view transposed [j][u]
    unsigned short* T3b = X3t + TE;                 // g natural (CH,N)
    unsigned short* xt  = T3b + TE;                 // 2*TE shorts (dead after conv3)
    unsigned short* Yp0 = xt;                       // alias
    unsigned short* Yp1 = xt + TE;                  // alias
    unsigned short* Yp2 = T3b;                      // alias (dead after transpose)
    unsigned short* Yp3 = xt + 2 * TE;              // fresh
    unsigned short* Wb  = Yp3 + TE;                 // 98304 shorts
    unsigned short* OWb = Wb + 98304;               // 32768 shorts
    float* Bf    = (float*)(OWb + 32768);           // 384
    float* OBf   = Bf + 384;                        // 256
    float* Lpart = OBf + 256;                       // 8 * BB * NN = 131072
    int*   Flag  = (int*)(Lpart + 131072);

    detect_kernel<<<1, 64, 0, stream>>>(tb, Flag);
    prep_kernel<<<dim3(515), 256, 0, stream>>>(tw, fw, gw, ow, tb, fb, gb, ob,
                                               Flag, Wb, OWb, Bf, OBf);
    xtrans_kernel<<<dim3(NN / 64, CC / 64, BB), 256, 0, stream>>>(x, Flag, xt);
    conv3_mfma_kernel<<<dim3(NN / 16, BB), 256, 0, stream>>>(xt, Wb, Bf, T1b, T2t, T3b);
    transpose_kernel<<<dim3(CHH / 64, NN / 64, BB), 256, 0, stream>>>(T3b, X3t, NN, CHH);
    stats_mfma_kernel<<<dim3(1024), 256, 0, stream>>>(T1b, T2t, Lpart);
    attn_mfma_kernel<<<dim3(512), 512, 0, stream>>>(T1b, T2t, X3t, Lpart, Yp0, Yp1, Yp2, Yp3);
    outconv_mfma_kernel<<<dim3(NN / 16, BB), 256, 0, stream>>>(x, Yp0, Yp1, Yp2, Yp3,
                                                               OWb, OBf, Flag, d_out);
}

// Round 4
// 208.175 us; speedup vs baseline: 1.3091x; 1.3091x over previous
//
#include <hip/hip_runtime.h>
#include <hip/hip_bf16.h>

#define BB 4
#define CC 256
#define CHH 128
#define NN 4096
#define KSHIFT 12.0f

typedef __attribute__((ext_vector_type(8))) short bf16x8;
typedef __attribute__((ext_vector_type(4))) float f32x4;

__device__ __forceinline__ float to_f(float v) { return v; }
__device__ __forceinline__ float to_f(__hip_bfloat16 v) { return __bfloat162float(v); }
__device__ __forceinline__ void st_f(float* p, float v) { *p = v; }
__device__ __forceinline__ void st_f(__hip_bfloat16* p, float v) { *p = __float2bfloat16(v); }
__device__ __forceinline__ unsigned short f2bf(float f) {
    __hip_bfloat16 h = __float2bfloat16(f);
    unsigned short u;
    __builtin_memcpy(&u, &h, 2);
    return u;
}
__device__ __forceinline__ bf16x8 ldb8(const unsigned short* p) { return *(const bf16x8*)p; }

// async global->LDS, 16 B per lane. LDS dest = wave-uniform base + lane*16.
__device__ __forceinline__ void gload_lds16(const unsigned short* g, unsigned short* l) {
    __builtin_amdgcn_global_load_lds(
        (const __attribute__((address_space(1))) unsigned int*)g,
        (__attribute__((address_space(3))) unsigned int*)l, 16, 0, 0);
}

// ---------------------------------------------------------------------------
// Kernel 0: wire-dtype detection (proven rounds 3-10 — keep).
// ---------------------------------------------------------------------------
__global__ void detect_kernel(const void* __restrict__ tb, int* __restrict__ flag) {
    if (threadIdx.x == 0) {
        const __hip_bfloat16* p = (const __hip_bfloat16*)tb;
        int big = 0, zeros = 0;
        for (int i = 0; i < 128; ++i) {
            float v = __bfloat162float(p[i]);
            if (!(fabsf(v) <= 0.5f)) big = 1;
            if ((i & 1) == 0 && v == 0.0f) zeros++;
        }
        *flag = (big || zeros >= 32) ? 1 : 0;
    }
}

// ---------------------------------------------------------------------------
// Kernel 1: convert all weights/biases once (proven round 6).
// ---------------------------------------------------------------------------
template <typename T>
__device__ __forceinline__ void prep_body(const T* tw, const T* fw, const T* gw, const T* ow,
                                          const T* tb2, const T* fb, const T* gb, const T* ob,
                                          unsigned short* Wb, unsigned short* OWb,
                                          float* Bf, float* OBf) {
    int idx = blockIdx.x * 256 + threadIdx.x;
    if (idx < 98304) {
        int cv = idx >> 15, rem = idx & 32767;
        const T* src = cv == 0 ? tw : (cv == 1 ? fw : gw);
        Wb[idx] = f2bf(to_f(src[rem]));
    } else if (idx < 131072) {
        OWb[idx - 98304] = f2bf(to_f(ow[idx - 98304]));
    } else if (idx < 131456) {
        int r = idx - 131072;
        int cv = r >> 7, j = r & 127;
        const T* src = cv == 0 ? tb2 : (cv == 1 ? fb : gb);
        Bf[r] = to_f(src[j]);
    } else if (idx < 131712) {
        OBf[idx - 131456] = to_f(ob[idx - 131456]);
    }
}

__global__ void prep_kernel(const void* tw, const void* fw, const void* gw, const void* ow,
                            const void* tb2, const void* fb, const void* gb, const void* ob,
                            const int* __restrict__ flag,
                            unsigned short* Wb, unsigned short* OWb, float* Bf, float* OBf) {
    if (*flag)
        prep_body<float>((const float*)tw, (const float*)fw, (const float*)gw, (const float*)ow,
                         (const float*)tb2, (const float*)fb, (const float*)gb, (const float*)ob,
                         Wb, OWb, Bf, OBf);
    else
        prep_body<__hip_bfloat16>((const __hip_bfloat16*)tw, (const __hip_bfloat16*)fw,
                                  (const __hip_bfloat16*)gw, (const __hip_bfloat16*)ow,
                                  (const __hip_bfloat16*)tb2, (const __hip_bfloat16*)fb,
                                  (const __hip_bfloat16*)gb, (const __hip_bfloat16*)ob,
                                  Wb, OWb, Bf, OBf);
}

// ---------------------------------------------------------------------------
// Kernel 2: xt[b][p][c] = bf16(x[b][c][p]) (proven round 6).
// ---------------------------------------------------------------------------
template <typename T>
__device__ __forceinline__ void xtrans_body(const T* __restrict__ x, unsigned short* __restrict__ xt) {
    int b = blockIdx.z;
    const T* in = x + (size_t)b * CC * NN;
    unsigned short* out = xt + (size_t)b * NN * CC;
    int p0 = blockIdx.x * 64, c0 = blockIdx.y * 64;
    __shared__ unsigned short t[64][68];
    int flat = threadIdx.x;
#pragma unroll
    for (int tt = 0; tt < 16; ++tt) {
        int id = flat + tt * 256;
        int rr = id >> 6, cc = id & 63;
        t[cc][rr] = f2bf(to_f(in[(size_t)(c0 + rr) * NN + p0 + cc]));
    }
    __syncthreads();
#pragma unroll
    for (int tt = 0; tt < 16; ++tt) {
        int id = flat + tt * 256;
        int pp = id >> 6, jj = id & 63;
        out[(size_t)(p0 + pp) * CC + c0 + jj] = t[pp][jj];
    }
}

__launch_bounds__(256)
__global__ void xtrans_kernel(const void* x, const int* __restrict__ flag,
                              unsigned short* __restrict__ xt) {
    if (*flag) xtrans_body<float>((const float*)x, xt);
    else       xtrans_body<__hip_bfloat16>((const __hip_bfloat16*)x, xt);
}

// ---------------------------------------------------------------------------
// Kernel 3: three 1x1 convs via MFMA.
//   cv=0 (theta): natural (CH,N) store -> T1b (== (N,CH) view).
//   cv=1 (phi):   T2t[p*128+o] written directly via 16x16 in-wave shfl
//                 transpose (audited: lane l' pulls D[o0+(l'&3)*4+k][p0+l'>>2]).
//   cv=2 (g):     natural store -> T3b. X3t CANNOT be fused (round-11 bug);
//                 standalone transpose reinstated below.
// ---------------------------------------------------------------------------
__launch_bounds__(256)
__global__ void conv3_mfma_kernel(const unsigned short* __restrict__ xt,
                                  const unsigned short* __restrict__ Wb,
                                  const float* __restrict__ Bf,
                                  unsigned short* __restrict__ T1b,
                                  unsigned short* __restrict__ T2t,
                                  unsigned short* __restrict__ T3b) {
    int b = blockIdx.y;
    int p0 = blockIdx.x * 16;
    int flat = threadIdx.x;
    int w = flat >> 6, lane = flat & 63, m = lane & 15, quad = lane >> 4;
    const unsigned short* xrow = xt + ((size_t)b * NN + p0 + m) * CC;
    bf16x8 xf[8];
#pragma unroll
    for (int kc = 0; kc < 8; ++kc)
        xf[kc] = ldb8(&xrow[kc * 32 + quad * 8]);
    unsigned short* t1  = T1b + (size_t)b * CHH * NN;
    unsigned short* t2t = T2t + (size_t)b * CHH * NN;   // [p][o], row stride 128
    unsigned short* t3  = T3b + (size_t)b * CHH * NN;   // natural (CH,N)
#pragma unroll
    for (int q = 0; q < 6; ++q) {
        int t = w * 6 + q;
        int cv = t >> 3, ot = t & 7;
        int o0 = ot * 16;
        const unsigned short* wrow = Wb + ((size_t)cv * CHH + o0 + m) * CC;
        f32x4 acc = {0.f, 0.f, 0.f, 0.f};
#pragma unroll
        for (int kc = 0; kc < 8; ++kc) {
            bf16x8 wf = ldb8(&wrow[kc * 32 + quad * 8]);
            acc = __builtin_amdgcn_mfma_f32_16x16x32_bf16(wf, xf[kc], acc, 0, 0, 0);
        }
        unsigned short hv[4];
#pragma unroll
        for (int r = 0; r < 4; ++r)
            hv[r] = f2bf(acc[r] + Bf[cv * CHH + o0 + quad * 4 + r]);
        if (cv == 1) {
            unsigned int lo = (unsigned int)hv[0] | ((unsigned int)hv[1] << 16);
            unsigned int hi = (unsigned int)hv[2] | ((unsigned int)hv[3] << 16);
            int src = (lane & 3) * 16 + (lane >> 2);
            unsigned int tlo = (unsigned int)__shfl((int)lo, src, 64);
            unsigned int thi = (unsigned int)__shfl((int)hi, src, 64);
            unsigned int* dst = (unsigned int*)&t2t[(size_t)(p0 + (lane >> 2)) * CHH +
                                                    o0 + (lane & 3) * 4];
            dst[0] = tlo;
            dst[1] = thi;
        } else {
            unsigned short* outp = (cv == 0) ? t1 : t3;
#pragma unroll
            for (int r = 0; r < 4; ++r)
                outp[(size_t)(o0 + quad * 4 + r) * NN + p0 + m] = hv[r];
        }
    }
}

// ---------------------------------------------------------------------------
// Kernel 4: generic bf16 tiled transpose (proven) — X3t only.
// ---------------------------------------------------------------------------
__launch_bounds__(256)
__global__ void transpose_kernel(const unsigned short* __restrict__ in,
                                 unsigned short* __restrict__ out, int R, int C) {
    int bz = blockIdx.z;
    in  += (size_t)bz * R * C;
    out += (size_t)bz * R * C;
    int c0 = blockIdx.x * 64, r0 = blockIdx.y * 64;
    __shared__ unsigned short t[64][68];
    int flat = threadIdx.x;
#pragma unroll
    for (int tt = 0; tt < 16; ++tt) {
        int id = flat + tt * 256;
        int r = id >> 6, c = id & 63;
        t[c][r] = in[(size_t)(r0 + r) * C + c0 + c];
    }
    __syncthreads();
#pragma unroll
    for (int tt = 0; tt < 16; ++tt) {
        int id = flat + tt * 256;
        int c = id >> 6, r = id & 63;
        out[(size_t)(c0 + c) * R + r0 + r] = t[c][r];
    }
}

// ---------------------------------------------------------------------------
// Kernel 5 (pass A): colsum exp(S-K). Round 12 double-buffered theta tile +
// single barrier per tile. Grid 1024 (4 blocks/CU x 4 waves = 4 waves/SIMD),
// LDS 32 KB. Unchanged this round.
// ---------------------------------------------------------------------------
__launch_bounds__(256)
__global__ void stats_mfma_kernel(const unsigned short* __restrict__ T1b,
                                  const unsigned short* __restrict__ T2t,
                                  float* __restrict__ Lpart) {
    int blk = blockIdx.x;
    int b = (blk & 7) >> 1;
    int rest = (blk >> 3) * 2 + (blk & 1);   // 0..255 = strip*8 + iq
    int strip = rest >> 3, iq = rest & 7;
    int ibase = iq * 512;
    int flat = threadIdx.x;
    int w = flat >> 6, lane = flat & 63, m = lane & 15, quad = lane >> 4;
    const unsigned short* A  = T1b + (size_t)b * CHH * NN;
    const unsigned short* Bt = T2t + (size_t)b * CHH * NN;
    __shared__ unsigned short th[2][64 * 128];   // double-buffered theta tile

    int u0w = strip * 128 + w * 32;           // this wave's 32-u window
    bf16x8 bfr[2][4];
#pragma unroll
    for (int g = 0; g < 2; ++g)
#pragma unroll
        for (int kc = 0; kc < 4; ++kc)
            bfr[g][kc] = ldb8(&Bt[(size_t)(u0w + g * 16 + m) * CHH + kc * 32 + quad * 8]);

#define STAGE_TH(dst, ii)                                                          \
    _Pragma("unroll")                                                              \
    for (int i_ = 0; i_ < 4; ++i_) {                                               \
        int sl = i_ * 256 + flat;                                                  \
        int r_ = sl >> 4, ch_ = sl & 15;                                           \
        int c_ = ch_ ^ (r_ & 7);                                                   \
        gload_lds16(&A[(size_t)((ii) + r_) * CHH + c_ * 8], &th[dst][sl * 8]);     \
    }

    float csum[2] = {0.f, 0.f};
    STAGE_TH(0, ibase);                      // prologue: tile 0
    __syncthreads();                         // tile 0 ready (vmcnt drained)
    int cur = 0;
    for (int t = 0; t < 8; ++t) {            // 8 i-tiles of 64 in this chunk
        if (t < 7) { STAGE_TH(cur ^ 1, ibase + (t + 1) * 64); }
        const unsigned short* thc = th[cur];
#pragma unroll
        for (int s = 0; s < 4; ++s) {
            int irow = s * 16 + m;
            bf16x8 af[4];
#pragma unroll
            for (int kc = 0; kc < 4; ++kc) {
                int ch = (kc * 4 + quad) ^ (irow & 7);
                af[kc] = *(const bf16x8*)&thc[irow * 128 + ch * 8];
            }
#pragma unroll
            for (int g = 0; g < 2; ++g) {
                f32x4 acc = {0.f, 0.f, 0.f, 0.f};
#pragma unroll
                for (int kc = 0; kc < 4; ++kc)
                    acc = __builtin_amdgcn_mfma_f32_16x16x32_bf16(af[kc], bfr[g][kc], acc, 0, 0, 0);
#pragma unroll
                for (int r = 0; r < 4; ++r)
                    csum[g] += __expf(acc[r] - KSHIFT);
            }
        }
        if (t < 7) {
            __syncthreads();                 // publishes tile t+1, protects buf t
            cur ^= 1;
        }
    }
#undef STAGE_TH
#pragma unroll
    for (int g = 0; g < 2; ++g) {
        csum[g] += __shfl_xor(csum[g], 16, 64);
        csum[g] += __shfl_xor(csum[g], 32, 64);
        if (lane < 16)
            Lpart[((size_t)iq * BB + b) * NN + u0w + g * 16 + m] = csum[g];
    }
}

// ---------------------------------------------------------------------------
// Kernel 6 (pass B): Y = P @ X3. ROUND 15: register-lean high-intensity
// split. 8 waves = 4 i-groups (32 rows) x 2 j-halves (64 cols). Per tile:
//   S:  wave computes S(32i x 32u) for u-half = its j-half index h
//       (8 bt reads -> 16 MFMAs, B shared across both 16-row accs),
//       P -> shared per-ig swizzled pT.  [barrier A publishes pT]
//   PV: wave computes Y(32i x 64j) over full 64-u K
//       (8 x3 reads + 4 pa reads -> 16 MFMAs). [barrier B protects pT/x3]
// 20 b128 reads feed 32 MFMAs (round-2 was 34) at yacc[2][4]=32 VGPRs
// (round-3's spill was yacc[2][8]=64 under a 64-VGPR cap — __launch_bounds__
// 2nd arg empirically caps as blocks/CU; use (512,2) -> cap >= 128).
// No merge epilogue: each wave owns a disjoint (i,j) output block.
// LDS 69,632 B -> 2 blocks/CU = 4 waves/SIMD.
// ---------------------------------------------------------------------------
__launch_bounds__(512, 2)
__global__ void attn_mfma_kernel(const unsigned short* __restrict__ T1b,
                                 const unsigned short* __restrict__ T2t,
                                 const unsigned short* __restrict__ X3t,
                                 const float* __restrict__ Lpart,
                                 unsigned short* __restrict__ Yp0,
                                 unsigned short* __restrict__ Yp1,
                                 unsigned short* __restrict__ Yp2,
                                 unsigned short* __restrict__ Yp3) {
    int blk = blockIdx.x;
    int b = (blk & 7) >> 1;
    int rest = (blk >> 3) * 2 + (blk & 1);   // 0..127 = it*4 + uc
    int it = rest >> 2, uc = rest & 3;
    int i0 = it * 128;
    unsigned short* Yp = uc == 0 ? Yp0 : (uc == 1 ? Yp1 : (uc == 2 ? Yp2 : Yp3));
    int flat = threadIdx.x;                   // 0..511
    int w = flat >> 6, lane = flat & 63, m = lane & 15, quad = lane >> 4;
    int ig = w & 3, h = w >> 2;               // i-group (32 rows), j-half/u-half
    const unsigned short* A  = T1b + (size_t)b * CHH * NN;
    const unsigned short* Bt = T2t + (size_t)b * CHH * NN;
    const unsigned short* X3 = X3t + (size_t)b * CHH * NN;

    // LDS arena, 69,632 B:
    //   [     0, 32768) bt   : phi^T tile, swizzled, dbuf 2 x 64x128 bf16
    //   [ 32768, 49152) x3   : X3 tile, swizzled, single 128x64 bf16
    //   [ 49152, 65536) pT   : per-ig P tiles [4][32 rows][64] bf16, XOR-swz
    //   [ 65536, 69632) llh  : 1024 f32 LL values
    __shared__ __align__(16) unsigned char smem[69632];
    unsigned short* bt0 = (unsigned short*)smem;
    unsigned short* x3s = (unsigned short*)(smem + 32768);
    unsigned short* pTg = (unsigned short*)(smem + 49152) + ig * 2048; // [32][64]
    float* llh = (float*)(smem + 65536);

    int ubeg = uc * 1024;
#pragma unroll
    for (int k = 0; k < 2; ++k) {             // LL prologue
        int idx = k * 512 + flat;
        int u = ubeg + idx;
        float s = 0.f;
#pragma unroll
        for (int c = 0; c < 8; ++c)
            s += Lpart[((size_t)c * BB + b) * NN + u];
        llh[idx] = logf(s) + KSHIFT;
    }

    int iw = i0 + ig * 32;                    // this wave's 32 i-rows
    int j0 = h * 64;                          // this wave's 64 j-cols
    bf16x8 ath[2][4];
#pragma unroll
    for (int g = 0; g < 2; ++g)
#pragma unroll
        for (int kc = 0; kc < 4; ++kc)
            ath[g][kc] = ldb8(&A[(size_t)(iw + g * 16 + m) * CHH + kc * 32 + quad * 8]);
    f32x4 yacc[2][4];
#pragma unroll
    for (int g = 0; g < 2; ++g)
#pragma unroll
        for (int js = 0; js < 4; ++js) yacc[g][js] = (f32x4){0.f, 0.f, 0.f, 0.f};

#define STAGE_BT(dst, uu)                                                          \
    _Pragma("unroll")                                                              \
    for (int i_ = 0; i_ < 2; ++i_) {          /* 16 KB */                          \
        int sl = i_ * 512 + flat;                                                  \
        int u_ = sl >> 4, ch_ = sl & 15;                                           \
        int c_ = ch_ ^ (u_ & 7);                                                   \
        gload_lds16(&Bt[(size_t)((uu) + u_) * CHH + c_ * 8],                       \
                    bt0 + (dst) * 8192 + sl * 8);                                  \
    }
#define STAGE_X3(uu)                                                               \
    _Pragma("unroll")                                                              \
    for (int i_ = 0; i_ < 2; ++i_) {          /* 16 KB */                          \
        int sl = i_ * 512 + flat;                                                  \
        int j_ = sl >> 3, ch_ = sl & 7;                                            \
        int c_ = ch_ ^ (j_ & 7);                                                   \
        gload_lds16(&X3[(size_t)j_ * NN + (uu) + c_ * 8], x3s + sl * 8);           \
    }

    STAGE_BT(0, ubeg);                        // prologue: bt tile 0 + x3 tile 0
    STAGE_X3(ubeg);
    __syncthreads();                          // staging drained + llh visible
    int cur = 0;
    for (int t = 0; t < 16; ++t) {
        int u0 = ubeg + t * 64;
        if (t < 15) { STAGE_BT(cur ^ 1, u0 + 64); }   // drains at barrier A
        const unsigned short* btc = bt0 + cur * 8192;
        // ---- S phase: S(32i x 32u-half h), exp, P -> shared swizzled pT ----
#pragma unroll
        for (int su = 0; su < 2; ++su) {
            int ul = h * 32 + su * 16 + m;    // u within tile (this wave's half)
            f32x4 a0 = {0.f, 0.f, 0.f, 0.f}, a1 = {0.f, 0.f, 0.f, 0.f};
#pragma unroll
            for (int kc = 0; kc < 4; ++kc) {
                int ch = (kc * 4 + quad) ^ (ul & 7);
                bf16x8 bf = *(const bf16x8*)&btc[ul * 128 + ch * 8];
                a0 = __builtin_amdgcn_mfma_f32_16x16x32_bf16(ath[0][kc], bf, a0, 0, 0, 0);
                a1 = __builtin_amdgcn_mfma_f32_16x16x32_bf16(ath[1][kc], bf, a1, 0, 0, 0);
            }
            float ll = llh[u0 - ubeg + ul];
#pragma unroll
            for (int r = 0; r < 4; ++r) {
                int r0 = quad * 4 + r;        // local row for g=0; g=1 adds 16
                pTg[r0 * 64 + ((ul >> 3) ^ (r0 & 7)) * 8 + (ul & 7)] =
                    f2bf(__expf(a0[r] - ll));
                pTg[(16 + r0) * 64 + ((ul >> 3) ^ (r0 & 7)) * 8 + (ul & 7)] =
                    f2bf(__expf(a1[r] - ll));
            }
        }
        __syncthreads();                      // A: pT published; x3(t)+bt(t+1) drained
        // ---- PV phase: Y(32i x 64j, cols j0..j0+63) over full 64-u K ----
#pragma unroll
        for (int ku = 0; ku < 2; ++ku) {
            bf16x8 pa0 = *(const bf16x8*)&pTg[m * 64 + ((ku * 4 + quad) ^ (m & 7)) * 8];
            bf16x8 pa1 = *(const bf16x8*)&pTg[(16 + m) * 64 + ((ku * 4 + quad) ^ (m & 7)) * 8];
#pragma unroll
            for (int js = 0; js < 4; ++js) {
                int j = j0 + js * 16 + m;
                int ch = (ku * 4 + quad) ^ (j & 7);
                bf16x8 xb = *(const bf16x8*)&x3s[j * 64 + ch * 8];
                yacc[0][js] = __builtin_amdgcn_mfma_f32_16x16x32_bf16(pa0, xb, yacc[0][js], 0, 0, 0);
                yacc[1][js] = __builtin_amdgcn_mfma_f32_16x16x32_bf16(pa1, xb, yacc[1][js], 0, 0, 0);
            }
        }
        __syncthreads();                      // B: pT + x3 reads done
        if (t < 15) { STAGE_X3(u0 + 64); }    // drains at A(t+1), under S(t+1)
        cur ^= 1;
    }
#undef STAGE_BT
#undef STAGE_X3
#pragma unroll
    for (int g = 0; g < 2; ++g)
#pragma unroll
        for (int js = 0; js < 4; ++js)
#pragma unroll
            for (int r = 0; r < 4; ++r)
                Yp[((size_t)b * NN + iw + g * 16 + quad * 4 + r) * CHH +
                   j0 + js * 16 + m] = f2bf(yacc[g][js][r]);
}

// ---------------------------------------------------------------------------
// Kernel 7: out = x + out_w @ (Yp0+Yp1+Yp2+Yp3)^T + out_b via MFMA
// (proven round 10; partials merged in the fp32 accumulator).
// ---------------------------------------------------------------------------
template <typename T>
__device__ __forceinline__ void outconv_body(const T* __restrict__ x,
                                             const unsigned short* __restrict__ Yp0,
                                             const unsigned short* __restrict__ Yp1,
                                             const unsigned short* __restrict__ Yp2,
                                             const unsigned short* __restrict__ Yp3,
                                             const unsigned short* __restrict__ OWb,
                                             const float* __restrict__ OBf,
                                             T* __restrict__ out) {
    int b = blockIdx.y;
    int p0 = blockIdx.x * 16;
    int flat = threadIdx.x;
    int w = flat >> 6, lane = flat & 63, m = lane & 15, quad = lane >> 4;
    size_t yoff = ((size_t)b * NN + p0 + m) * CHH;
    const unsigned short* yrows[4] = {Yp0 + yoff, Yp1 + yoff, Yp2 + yoff, Yp3 + yoff};
    bf16x8 yf[4][4];
#pragma unroll
    for (int pz = 0; pz < 4; ++pz)
#pragma unroll
        for (int kc = 0; kc < 4; ++kc)
            yf[pz][kc] = ldb8(&yrows[pz][kc * 32 + quad * 8]);
#pragma unroll
    for (int q = 0; q < 4; ++q) {
        int o0 = (w * 4 + q) * 16;
        const unsigned short* wrow = OWb + (size_t)(o0 + m) * CHH;
        f32x4 acc = {0.f, 0.f, 0.f, 0.f};
#pragma unroll
        for (int kc = 0; kc < 4; ++kc) {
            bf16x8 aw = ldb8(&wrow[kc * 32 + quad * 8]);
#pragma unroll
            for (int pz = 0; pz < 4; ++pz)
                acc = __builtin_amdgcn_mfma_f32_16x16x32_bf16(aw, yf[pz][kc], acc, 0, 0, 0);
        }
#pragma unroll
        for (int r = 0; r < 4; ++r) {
            int co = o0 + quad * 4 + r;
            size_t oi = ((size_t)b * CC + co) * NN + p0 + m;
            st_f(&out[oi], acc[r] + OBf[co] + to_f(x[oi]));
        }
    }
}

__launch_bounds__(256)
__global__ void outconv_mfma_kernel(const void* x,
                                    const unsigned short* __restrict__ Yp0,
                                    const unsigned short* __restrict__ Yp1,
                                    const unsigned short* __restrict__ Yp2,
                                    const unsigned short* __restrict__ Yp3,
                                    const unsigned short* __restrict__ OWb,
                                    const float* __restrict__ OBf,
                                    const int* __restrict__ flag, void* out) {
    if (*flag)
        outconv_body<float>((const float*)x, Yp0, Yp1, Yp2, Yp3, OWb, OBf, (float*)out);
    else
        outconv_body<__hip_bfloat16>((const __hip_bfloat16*)x, Yp0, Yp1, Yp2, Yp3, OWb, OBf,
                                     (__hip_bfloat16*)out);
}

extern "C" void kernel_launch(void* const* d_in, const int* in_sizes, int n_in,
                              void* d_out, int out_size, void* d_ws, size_t ws_size,
                              hipStream_t stream) {
    const void* x  = d_in[0];
    const void* tw = d_in[1];
    const void* tb = d_in[2];
    const void* fw = d_in[3];
    const void* fb = d_in[4];
    const void* gw = d_in[5];
    const void* gb = d_in[6];
    const void* ow = d_in[7];
    const void* ob = d_in[8];

    // Workspace (~30 MB): conv3 writes T1b natural, T2t fused-transposed,
    // T3b natural; transpose T3b -> X3t. Aliases: Yp0/Yp1 <- xt (dead after
    // conv3), Yp2 <- T3b (dead after the X3t transpose), Yp3 fresh.
    const size_t TE = (size_t)BB * CHH * NN;        // 2,097,152
    unsigned short* T1b = (unsigned short*)d_ws;
    unsigned short* T2t = T1b + TE;                 // phi transposed [p][o]
    unsigned short* X3t = T2t + TE;                 // g-view transposed [j][u]
    unsigned short* T3b = X3t + TE;                 // g natural (CH,N)
    unsigned short* xt  = T3b + TE;                 // 2*TE shorts (dead after conv3)
    unsigned short* Yp0 = xt;                       // alias
    unsigned short* Yp1 = xt + TE;                  // alias
    unsigned short* Yp2 = T3b;                      // alias (dead after transpose)
    unsigned short* Yp3 = xt + 2 * TE;              // fresh
    unsigned short* Wb  = Yp3 + TE;                 // 98304 shorts
    unsigned short* OWb = Wb + 98304;               // 32768 shorts
    float* Bf    = (float*)(OWb + 32768);           // 384
    float* OBf   = Bf + 384;                        // 256
    float* Lpart = OBf + 256;                       // 8 * BB * NN = 131072
    int*   Flag  = (int*)(Lpart + 131072);

    detect_kernel<<<1, 64, 0, stream>>>(tb, Flag);
    prep_kernel<<<dim3(515), 256, 0, stream>>>(tw, fw, gw, ow, tb, fb, gb, ob,
                                               Flag, Wb, OWb, Bf, OBf);
    xtrans_kernel<<<dim3(NN / 64, CC / 64, BB), 256, 0, stream>>>(x, Flag, xt);
    conv3_mfma_kernel<<<dim3(NN / 16, BB), 256, 0, stream>>>(xt, Wb, Bf, T1b, T2t, T3b);
    transpose_kernel<<<dim3(CHH / 64, NN / 64, BB), 256, 0, stream>>>(T3b, X3t, NN, CHH);
    stats_mfma_kernel<<<dim3(1024), 256, 0, stream>>>(T1b, T2t, Lpart);
    attn_mfma_kernel<<<dim3(512), 512, 0, stream>>>(T1b, T2t, X3t, Lpart, Yp0, Yp1, Yp2, Yp3);
    outconv_mfma_kernel<<<dim3(NN / 16, BB), 256, 0, stream>>>(x, Yp0, Yp1, Yp2, Yp3,
                                                               OWb, OBf, Flag, d_out);
}

// Round 5
// 208.166 us; speedup vs baseline: 1.3092x; 1.0000x over previous
//
#include <hip/hip_runtime.h>
#include <hip/hip_bf16.h>

#define BB 4
#define CC 256
#define CHH 128
#define NN 4096
#define KSHIFT 12.0f

typedef __attribute__((ext_vector_type(8))) short bf16x8;
typedef __attribute__((ext_vector_type(4))) float f32x4;

__device__ __forceinline__ float to_f(float v) { return v; }
__device__ __forceinline__ float to_f(__hip_bfloat16 v) { return __bfloat162float(v); }
__device__ __forceinline__ void st_f(float* p, float v) { *p = v; }
__device__ __forceinline__ void st_f(__hip_bfloat16* p, float v) { *p = __float2bfloat16(v); }
__device__ __forceinline__ unsigned short f2bf(float f) {
    __hip_bfloat16 h = __float2bfloat16(f);
    unsigned short u;
    __builtin_memcpy(&u, &h, 2);
    return u;
}
__device__ __forceinline__ bf16x8 ldb8(const unsigned short* p) { return *(const bf16x8*)p; }

// async global->LDS, 16 B per lane. LDS dest = wave-uniform base + lane*16.
__device__ __forceinline__ void gload_lds16(const unsigned short* g, unsigned short* l) {
    __builtin_amdgcn_global_load_lds(
        (const __attribute__((address_space(1))) unsigned int*)g,
        (__attribute__((address_space(3))) unsigned int*)l, 16, 0, 0);
}

// ---------------------------------------------------------------------------
// Kernel 0: wire-dtype detection. ROUND 16: wave-parallel (was 128 serial
// loads on thread 0). Same predicate semantics.
// ---------------------------------------------------------------------------
__global__ void detect_kernel(const void* __restrict__ tb, int* __restrict__ flag) {
    const __hip_bfloat16* p = (const __hip_bfloat16*)tb;
    int i = threadIdx.x;                     // 64 lanes, 2 elems each
    int big = 0, zero_even = 0;
#pragma unroll
    for (int k = 0; k < 2; ++k) {
        int idx = i * 2 + k;
        float v = __bfloat162float(p[idx]);
        if (!(fabsf(v) <= 0.5f)) big = 1;
        if ((idx & 1) == 0 && v == 0.0f) zero_even = 1;
    }
    unsigned long long bigm = __ballot(big);
    unsigned long long zm = __ballot(zero_even);
    if (i == 0) *flag = (bigm != 0ULL || __popcll(zm) >= 32) ? 1 : 0;
}

// ---------------------------------------------------------------------------
// Kernel 1: convert all weights/biases once (proven round 6).
// ---------------------------------------------------------------------------
template <typename T>
__device__ __forceinline__ void prep_body(const T* tw, const T* fw, const T* gw, const T* ow,
                                          const T* tb2, const T* fb, const T* gb, const T* ob,
                                          unsigned short* Wb, unsigned short* OWb,
                                          float* Bf, float* OBf) {
    int idx = blockIdx.x * 256 + threadIdx.x;
    if (idx < 98304) {
        int cv = idx >> 15, rem = idx & 32767;
        const T* src = cv == 0 ? tw : (cv == 1 ? fw : gw);
        Wb[idx] = f2bf(to_f(src[rem]));
    } else if (idx < 131072) {
        OWb[idx - 98304] = f2bf(to_f(ow[idx - 98304]));
    } else if (idx < 131456) {
        int r = idx - 131072;
        int cv = r >> 7, j = r & 127;
        const T* src = cv == 0 ? tb2 : (cv == 1 ? fb : gb);
        Bf[r] = to_f(src[j]);
    } else if (idx < 131712) {
        OBf[idx - 131456] = to_f(ob[idx - 131456]);
    }
}

__global__ void prep_kernel(const void* tw, const void* fw, const void* gw, const void* ow,
                            const void* tb2, const void* fb, const void* gb, const void* ob,
                            const int* __restrict__ flag,
                            unsigned short* Wb, unsigned short* OWb, float* Bf, float* OBf) {
    if (*flag)
        prep_body<float>((const float*)tw, (const float*)fw, (const float*)gw, (const float*)ow,
                         (const float*)tb2, (const float*)fb, (const float*)gb, (const float*)ob,
                         Wb, OWb, Bf, OBf);
    else
        prep_body<__hip_bfloat16>((const __hip_bfloat16*)tw, (const __hip_bfloat16*)fw,
                                  (const __hip_bfloat16*)gw, (const __hip_bfloat16*)ow,
                                  (const __hip_bfloat16*)tb2, (const __hip_bfloat16*)fb,
                                  (const __hip_bfloat16*)gb, (const __hip_bfloat16*)ob,
                                  Wb, OWb, Bf, OBf);
}

// ---------------------------------------------------------------------------
// Kernel 2: xt[b][p][c] = bf16(x[b][c][p]) (proven round 6).
// ---------------------------------------------------------------------------
template <typename T>
__device__ __forceinline__ void xtrans_body(const T* __restrict__ x, unsigned short* __restrict__ xt) {
    int b = blockIdx.z;
    const T* in = x + (size_t)b * CC * NN;
    unsigned short* out = xt + (size_t)b * NN * CC;
    int p0 = blockIdx.x * 64, c0 = blockIdx.y * 64;
    __shared__ unsigned short t[64][68];
    int flat = threadIdx.x;
#pragma unroll
    for (int tt = 0; tt < 16; ++tt) {
        int id = flat + tt * 256;
        int rr = id >> 6, cc = id & 63;
        t[cc][rr] = f2bf(to_f(in[(size_t)(c0 + rr) * NN + p0 + cc]));
    }
    __syncthreads();
#pragma unroll
    for (int tt = 0; tt < 16; ++tt) {
        int id = flat + tt * 256;
        int pp = id >> 6, jj = id & 63;
        out[(size_t)(p0 + pp) * CC + c0 + jj] = t[pp][jj];
    }
}

__launch_bounds__(256)
__global__ void xtrans_kernel(const void* x, const int* __restrict__ flag,
                              unsigned short* __restrict__ xt) {
    if (*flag) xtrans_body<float>((const float*)x, xt);
    else       xtrans_body<__hip_bfloat16>((const __hip_bfloat16*)x, xt);
}

// ---------------------------------------------------------------------------
// Kernel 3: three 1x1 convs via MFMA (proven; see round-11 note on X3t).
// ---------------------------------------------------------------------------
__launch_bounds__(256)
__global__ void conv3_mfma_kernel(const unsigned short* __restrict__ xt,
                                  const unsigned short* __restrict__ Wb,
                                  const float* __restrict__ Bf,
                                  unsigned short* __restrict__ T1b,
                                  unsigned short* __restrict__ T2t,
                                  unsigned short* __restrict__ T3b) {
    int b = blockIdx.y;
    int p0 = blockIdx.x * 16;
    int flat = threadIdx.x;
    int w = flat >> 6, lane = flat & 63, m = lane & 15, quad = lane >> 4;
    const unsigned short* xrow = xt + ((size_t)b * NN + p0 + m) * CC;
    bf16x8 xf[8];
#pragma unroll
    for (int kc = 0; kc < 8; ++kc)
        xf[kc] = ldb8(&xrow[kc * 32 + quad * 8]);
    unsigned short* t1  = T1b + (size_t)b * CHH * NN;
    unsigned short* t2t = T2t + (size_t)b * CHH * NN;   // [p][o], row stride 128
    unsigned short* t3  = T3b + (size_t)b * CHH * NN;   // natural (CH,N)
#pragma unroll
    for (int q = 0; q < 6; ++q) {
        int t = w * 6 + q;
        int cv = t >> 3, ot = t & 7;
        int o0 = ot * 16;
        const unsigned short* wrow = Wb + ((size_t)cv * CHH + o0 + m) * CC;
        f32x4 acc = {0.f, 0.f, 0.f, 0.f};
#pragma unroll
        for (int kc = 0; kc < 8; ++kc) {
            bf16x8 wf = ldb8(&wrow[kc * 32 + quad * 8]);
            acc = __builtin_amdgcn_mfma_f32_16x16x32_bf16(wf, xf[kc], acc, 0, 0, 0);
        }
        unsigned short hv[4];
#pragma unroll
        for (int r = 0; r < 4; ++r)
            hv[r] = f2bf(acc[r] + Bf[cv * CHH + o0 + quad * 4 + r]);
        if (cv == 1) {
            unsigned int lo = (unsigned int)hv[0] | ((unsigned int)hv[1] << 16);
            unsigned int hi = (unsigned int)hv[2] | ((unsigned int)hv[3] << 16);
            int src = (lane & 3) * 16 + (lane >> 2);
            unsigned int tlo = (unsigned int)__shfl((int)lo, src, 64);
            unsigned int thi = (unsigned int)__shfl((int)hi, src, 64);
            unsigned int* dst = (unsigned int*)&t2t[(size_t)(p0 + (lane >> 2)) * CHH +
                                                    o0 + (lane & 3) * 4];
            dst[0] = tlo;
            dst[1] = thi;
        } else {
            unsigned short* outp = (cv == 0) ? t1 : t3;
#pragma unroll
            for (int r = 0; r < 4; ++r)
                outp[(size_t)(o0 + quad * 4 + r) * NN + p0 + m] = hv[r];
        }
    }
}

// ---------------------------------------------------------------------------
// Kernel 4: generic bf16 tiled transpose (proven) — X3t only.
// ---------------------------------------------------------------------------
__launch_bounds__(256)
__global__ void transpose_kernel(const unsigned short* __restrict__ in,
                                 unsigned short* __restrict__ out, int R, int C) {
    int bz = blockIdx.z;
    in  += (size_t)bz * R * C;
    out += (size_t)bz * R * C;
    int c0 = blockIdx.x * 64, r0 = blockIdx.y * 64;
    __shared__ unsigned short t[64][68];
    int flat = threadIdx.x;
#pragma unroll
    for (int tt = 0; tt < 16; ++tt) {
        int id = flat + tt * 256;
        int r = id >> 6, c = id & 63;
        t[c][r] = in[(size_t)(r0 + r) * C + c0 + c];
    }
    __syncthreads();
#pragma unroll
    for (int tt = 0; tt < 16; ++tt) {
        int id = flat + tt * 256;
        int c = id >> 6, r = id & 63;
        out[(size_t)(c0 + c) * R + r0 + r] = t[c][r];
    }
}

// ---------------------------------------------------------------------------
// Kernel 5 (pass A): colsum exp(S-K). Round 12 double-buffered theta tile +
// single barrier per tile. Grid 1024 (4 blocks/CU x 4 waves = 4 waves/SIMD),
// LDS 32 KB. Unchanged this round.
// ---------------------------------------------------------------------------
__launch_bounds__(256)
__global__ void stats_mfma_kernel(const unsigned short* __restrict__ T1b,
                                  const unsigned short* __restrict__ T2t,
                                  float* __restrict__ Lpart) {
    int blk = blockIdx.x;
    int b = (blk & 7) >> 1;
    int rest = (blk >> 3) * 2 + (blk & 1);   // 0..255 = strip*8 + iq
    int strip = rest >> 3, iq = rest & 7;
    int ibase = iq * 512;
    int flat = threadIdx.x;
    int w = flat >> 6, lane = flat & 63, m = lane & 15, quad = lane >> 4;
    const unsigned short* A  = T1b + (size_t)b * CHH * NN;
    const unsigned short* Bt = T2t + (size_t)b * CHH * NN;
    __shared__ unsigned short th[2][64 * 128];   // double-buffered theta tile

    int u0w = strip * 128 + w * 32;           // this wave's 32-u window
    bf16x8 bfr[2][4];
#pragma unroll
    for (int g = 0; g < 2; ++g)
#pragma unroll
        for (int kc = 0; kc < 4; ++kc)
            bfr[g][kc] = ldb8(&Bt[(size_t)(u0w + g * 16 + m) * CHH + kc * 32 + quad * 8]);

#define STAGE_TH(dst, ii)                                                          \
    _Pragma("unroll")                                                              \
    for (int i_ = 0; i_ < 4; ++i_) {                                               \
        int sl = i_ * 256 + flat;                                                  \
        int r_ = sl >> 4, ch_ = sl & 15;                                           \
        int c_ = ch_ ^ (r_ & 7);                                                   \
        gload_lds16(&A[(size_t)((ii) + r_) * CHH + c_ * 8], &th[dst][sl * 8]);     \
    }

    float csum[2] = {0.f, 0.f};
    STAGE_TH(0, ibase);                      // prologue: tile 0
    __syncthreads();                         // tile 0 ready (vmcnt drained)
    int cur = 0;
    for (int t = 0; t < 8; ++t) {            // 8 i-tiles of 64 in this chunk
        if (t < 7) { STAGE_TH(cur ^ 1, ibase + (t + 1) * 64); }
        const unsigned short* thc = th[cur];
#pragma unroll
        for (int s = 0; s < 4; ++s) {
            int irow = s * 16 + m;
            bf16x8 af[4];
#pragma unroll
            for (int kc = 0; kc < 4; ++kc) {
                int ch = (kc * 4 + quad) ^ (irow & 7);
                af[kc] = *(const bf16x8*)&thc[irow * 128 + ch * 8];
            }
#pragma unroll
            for (int g = 0; g < 2; ++g) {
                f32x4 acc = {0.f, 0.f, 0.f, 0.f};
#pragma unroll
                for (int kc = 0; kc < 4; ++kc)
                    acc = __builtin_amdgcn_mfma_f32_16x16x32_bf16(af[kc], bfr[g][kc], acc, 0, 0, 0);
#pragma unroll
                for (int r = 0; r < 4; ++r)
                    csum[g] += __expf(acc[r] - KSHIFT);
            }
        }
        if (t < 7) {
            __syncthreads();                 // publishes tile t+1, protects buf t
            cur ^= 1;
        }
    }
#undef STAGE_TH
#pragma unroll
    for (int g = 0; g < 2; ++g) {
        csum[g] += __shfl_xor(csum[g], 16, 64);
        csum[g] += __shfl_xor(csum[g], 32, 64);
        if (lane < 16)
            Lpart[((size_t)iq * BB + b) * NN + u0w + g * 16 + m] = csum[g];
    }
}

// ---------------------------------------------------------------------------
// Kernel 6 (pass B): Y = P @ X3. ROUND 16: (W_i,W_j) = (2,4) partition —
// 8 waves = 2 i-halves (64 rows, ath[4][4]) x 4 j/u-quarters. Per tile:
//   S:  wave computes S(64i x 16u) for u-quarter jq (4 bt reads -> 16 MFMA,
//       one bt frag feeds 4 row-accs), P -> shared per-ig swizzled pT[64][64].
//   PV: wave computes Y(64i x 32j) over full 64-u (8 pa + 4 x3 reads ->
//       16 MFMA).
// LDS bytes/block/tile: (2*W_i + W_j)*16KB = 128KB (was 160KB, -20%).
// 16 b128 reads/wave/tile (was 20). VGPR base ath64+yacc32=96, cap 128
// via (512,2) (validated round 4; round-3's (512,4) capped at 64 = spill).
// LDS arena unchanged 69,632 B -> 2 blocks/CU = 4 waves/SIMD.
// ---------------------------------------------------------------------------
__launch_bounds__(512, 2)
__global__ void attn_mfma_kernel(const unsigned short* __restrict__ T1b,
                                 const unsigned short* __restrict__ T2t,
                                 const unsigned short* __restrict__ X3t,
                                 const float* __restrict__ Lpart,
                                 unsigned short* __restrict__ Yp0,
                                 unsigned short* __restrict__ Yp1,
                                 unsigned short* __restrict__ Yp2,
                                 unsigned short* __restrict__ Yp3) {
    int blk = blockIdx.x;
    int b = (blk & 7) >> 1;
    int rest = (blk >> 3) * 2 + (blk & 1);   // 0..127 = it*4 + uc
    int it = rest >> 2, uc = rest & 3;
    int i0 = it * 128;
    unsigned short* Yp = uc == 0 ? Yp0 : (uc == 1 ? Yp1 : (uc == 2 ? Yp2 : Yp3));
    int flat = threadIdx.x;                   // 0..511
    int w = flat >> 6, lane = flat & 63, m = lane & 15, quad = lane >> 4;
    int jq = w & 3, ig = w >> 2;              // j/u-quarter, i-half (64 rows)
    const unsigned short* A  = T1b + (size_t)b * CHH * NN;
    const unsigned short* Bt = T2t + (size_t)b * CHH * NN;
    const unsigned short* X3 = X3t + (size_t)b * CHH * NN;

    // LDS arena, 69,632 B:
    //   [     0, 32768) bt   : phi^T tile, swizzled, dbuf 2 x 64x128 bf16
    //   [ 32768, 49152) x3   : X3 tile, swizzled, single 128x64 bf16
    //   [ 49152, 65536) pT   : per-ig P tiles [2][64 rows][64 u] bf16, XOR-swz
    //   [ 65536, 69632) llh  : 1024 f32 LL values
    __shared__ __align__(16) unsigned char smem[69632];
    unsigned short* bt0 = (unsigned short*)smem;
    unsigned short* x3s = (unsigned short*)(smem + 32768);
    unsigned short* pTg = (unsigned short*)(smem + 49152) + ig * 4096; // [64][64]
    float* llh = (float*)(smem + 65536);

    int ubeg = uc * 1024;
#pragma unroll
    for (int k = 0; k < 2; ++k) {             // LL prologue
        int idx = k * 512 + flat;
        int u = ubeg + idx;
        float s = 0.f;
#pragma unroll
        for (int c = 0; c < 8; ++c)
            s += Lpart[((size_t)c * BB + b) * NN + u];
        llh[idx] = logf(s) + KSHIFT;
    }

    int iw = i0 + ig * 64;                    // this wave's 64 i-rows
    int j0 = jq * 32;                         // this wave's 32 j-cols
    bf16x8 ath[4][4];
#pragma unroll
    for (int g = 0; g < 4; ++g)
#pragma unroll
        for (int kc = 0; kc < 4; ++kc)
            ath[g][kc] = ldb8(&A[(size_t)(iw + g * 16 + m) * CHH + kc * 32 + quad * 8]);
    f32x4 yacc[4][2];
#pragma unroll
    for (int g = 0; g < 4; ++g)
#pragma unroll
        for (int js = 0; js < 2; ++js) yacc[g][js] = (f32x4){0.f, 0.f, 0.f, 0.f};

#define STAGE_BT(dst, uu)                                                          \
    _Pragma("unroll")                                                              \
    for (int i_ = 0; i_ < 2; ++i_) {          /* 16 KB */                          \
        int sl = i_ * 512 + flat;                                                  \
        int u_ = sl >> 4, ch_ = sl & 15;                                           \
        int c_ = ch_ ^ (u_ & 7);                                                   \
        gload_lds16(&Bt[(size_t)((uu) + u_) * CHH + c_ * 8],                       \
                    bt0 + (dst) * 8192 + sl * 8);                                  \
    }
#define STAGE_X3(uu)                                                               \
    _Pragma("unroll")                                                              \
    for (int i_ = 0; i_ < 2; ++i_) {          /* 16 KB */                          \
        int sl = i_ * 512 + flat;                                                  \
        int j_ = sl >> 3, ch_ = sl & 7;                                            \
        int c_ = ch_ ^ (j_ & 7);                                                   \
        gload_lds16(&X3[(size_t)j_ * NN + (uu) + c_ * 8], x3s + sl * 8);           \
    }

    STAGE_BT(0, ubeg);                        // prologue: bt tile 0 + x3 tile 0
    STAGE_X3(ubeg);
    __syncthreads();                          // staging drained + llh visible
    int cur = 0;
    for (int t = 0; t < 16; ++t) {
        int u0 = ubeg + t * 64;
        if (t < 15) { STAGE_BT(cur ^ 1, u0 + 64); }   // drains at barrier A
        const unsigned short* btc = bt0 + cur * 8192;
        // ---- S phase: S(64i x 16u-quarter jq), exp, P -> shared pT ----
        {
            int ul = jq * 16 + m;             // u within tile (this wave's slice)
            f32x4 sa[4];
#pragma unroll
            for (int g = 0; g < 4; ++g) sa[g] = (f32x4){0.f, 0.f, 0.f, 0.f};
#pragma unroll
            for (int kc = 0; kc < 4; ++kc) {
                int ch = (kc * 4 + quad) ^ (ul & 7);
                bf16x8 bf = *(const bf16x8*)&btc[ul * 128 + ch * 8];
#pragma unroll
                for (int g = 0; g < 4; ++g)
                    sa[g] = __builtin_amdgcn_mfma_f32_16x16x32_bf16(ath[g][kc], bf, sa[g], 0, 0, 0);
            }
            float ll = llh[t * 64 + ul];
#pragma unroll
            for (int r = 0; r < 4; ++r) {
                int rr = quad * 4 + r;        // (16g + rr) & 7 == rr & 7
                int sw = ((ul >> 3) ^ (rr & 7)) * 8 + (ul & 7);
#pragma unroll
                for (int g = 0; g < 4; ++g)
                    pTg[(g * 16 + rr) * 64 + sw] = f2bf(__expf(sa[g][r] - ll));
            }
        }
        __syncthreads();                      // A: pT published; x3(t)+bt(t+1) drained
        // ---- PV phase: Y(64i x 32j, cols j0..j0+31) over full 64-u K ----
#pragma unroll
        for (int ku = 0; ku < 2; ++ku) {
            bf16x8 pa[4];
#pragma unroll
            for (int g = 0; g < 4; ++g)
                pa[g] = *(const bf16x8*)&pTg[(g * 16 + m) * 64 +
                                             ((ku * 4 + quad) ^ (m & 7)) * 8];
#pragma unroll
            for (int js = 0; js < 2; ++js) {
                int j = j0 + js * 16 + m;
                int ch = (ku * 4 + quad) ^ (j & 7);
                bf16x8 xb = *(const bf16x8*)&x3s[j * 64 + ch * 8];
#pragma unroll
                for (int g = 0; g < 4; ++g)
                    yacc[g][js] = __builtin_amdgcn_mfma_f32_16x16x32_bf16(pa[g], xb, yacc[g][js], 0, 0, 0);
            }
        }
        __syncthreads();                      // B: pT + x3 reads done
        if (t < 15) { STAGE_X3(u0 + 64); }    // drains at A(t+1), under S(t+1)
        cur ^= 1;
    }
#undef STAGE_BT
#undef STAGE_X3
#pragma unroll
    for (int g = 0; g < 4; ++g)
#pragma unroll
        for (int js = 0; js < 2; ++js)
#pragma unroll
            for (int r = 0; r < 4; ++r)
                Yp[((size_t)b * NN + iw + g * 16 + quad * 4 + r) * CHH +
                   j0 + js * 16 + m] = f2bf(yacc[g][js][r]);
}

// ---------------------------------------------------------------------------
// Kernel 7: out = x + out_w @ (Yp0+Yp1+Yp2+Yp3)^T + out_b via MFMA
// (proven round 10; partials merged in the fp32 accumulator).
// ---------------------------------------------------------------------------
template <typename T>
__device__ __forceinline__ void outconv_body(const T* __restrict__ x,
                                             const unsigned short* __restrict__ Yp0,
                                             const unsigned short* __restrict__ Yp1,
                                             const unsigned short* __restrict__ Yp2,
                                             const unsigned short* __restrict__ Yp3,
                                             const unsigned short* __restrict__ OWb,
                                             const float* __restrict__ OBf,
                                             T* __restrict__ out) {
    int b = blockIdx.y;
    int p0 = blockIdx.x * 16;
    int flat = threadIdx.x;
    int w = flat >> 6, lane = flat & 63, m = lane & 15, quad = lane >> 4;
    size_t yoff = ((size_t)b * NN + p0 + m) * CHH;
    const unsigned short* yrows[4] = {Yp0 + yoff, Yp1 + yoff, Yp2 + yoff, Yp3 + yoff};
    bf16x8 yf[4][4];
#pragma unroll
    for (int pz = 0; pz < 4; ++pz)
#pragma unroll
        for (int kc = 0; kc < 4; ++kc)
            yf[pz][kc] = ldb8(&yrows[pz][kc * 32 + quad * 8]);
#pragma unroll
    for (int q = 0; q < 4; ++q) {
        int o0 = (w * 4 + q) * 16;
        const unsigned short* wrow = OWb + (size_t)(o0 + m) * CHH;
        f32x4 acc = {0.f, 0.f, 0.f, 0.f};
#pragma unroll
        for (int kc = 0; kc < 4; ++kc) {
            bf16x8 aw = ldb8(&wrow[kc * 32 + quad * 8]);
#pragma unroll
            for (int pz = 0; pz < 4; ++pz)
                acc = __builtin_amdgcn_mfma_f32_16x16x32_bf16(aw, yf[pz][kc], acc, 0, 0, 0);
        }
#pragma unroll
        for (int r = 0; r < 4; ++r) {
            int co = o0 + quad * 4 + r;
            size_t oi = ((size_t)b * CC + co) * NN + p0 + m;
            st_f(&out[oi], acc[r] + OBf[co] + to_f(x[oi]));
        }
    }
}

__launch_bounds__(256)
__global__ void outconv_mfma_kernel(const void* x,
                                    const unsigned short* __restrict__ Yp0,
                                    const unsigned short* __restrict__ Yp1,
                                    const unsigned short* __restrict__ Yp2,
                                    const unsigned short* __restrict__ Yp3,
                                    const unsigned short* __restrict__ OWb,
                                    const float* __restrict__ OBf,
                                    const int* __restrict__ flag, void* out) {
    if (*flag)
        outconv_body<float>((const float*)x, Yp0, Yp1, Yp2, Yp3, OWb, OBf, (float*)out);
    else
        outconv_body<__hip_bfloat16>((const __hip_bfloat16*)x, Yp0, Yp1, Yp2, Yp3, OWb, OBf,
                                     (__hip_bfloat16*)out);
}

extern "C" void kernel_launch(void* const* d_in, const int* in_sizes, int n_in,
                              void* d_out, int out_size, void* d_ws, size_t ws_size,
                              hipStream_t stream) {
    const void* x  = d_in[0];
    const void* tw = d_in[1];
    const void* tb = d_in[2];
    const void* fw = d_in[3];
    const void* fb = d_in[4];
    const void* gw = d_in[5];
    const void* gb = d_in[6];
    const void* ow = d_in[7];
    const void* ob = d_in[8];

    // Workspace (~30 MB): conv3 writes T1b natural, T2t fused-transposed,
    // T3b natural; transpose T3b -> X3t. Aliases: Yp0/Yp1 <- xt (dead after
    // conv3), Yp2 <- T3b (dead after the X3t transpose), Yp3 fresh.
    const size_t TE = (size_t)BB * CHH * NN;        // 2,097,152
    unsigned short* T1b = (unsigned short*)d_ws;
    unsigned short* T2t = T1b + TE;                 // phi transposed [p][o]
    unsigned short* X3t = T2t + TE;                 // g-view transposed [j][u]
    unsigned short* T3b = X3t + TE;                 // g natural (CH,N)
    unsigned short* xt  = T3b + TE;                 // 2*TE shorts (dead after conv3)
    unsigned short* Yp0 = xt;                       // alias
    unsigned short* Yp1 = xt + TE;                  // alias
    unsigned short* Yp2 = T3b;                      // alias (dead after transpose)
    unsigned short* Yp3 = xt + 2 * TE;              // fresh
    unsigned short* Wb  = Yp3 + TE;                 // 98304 shorts
    unsigned short* OWb = Wb + 98304;               // 32768 shorts
    float* Bf    = (float*)(OWb + 32768);           // 384
    float* OBf   = Bf + 384;                        // 256
    float* Lpart = OBf + 256;                       // 8 * BB * NN = 131072
    int*   Flag  = (int*)(Lpart + 131072);

    detect_kernel<<<1, 64, 0, stream>>>(tb, Flag);
    prep_kernel<<<dim3(515), 256, 0, stream>>>(tw, fw, gw, ow, tb, fb, gb, ob,
                                               Flag, Wb, OWb, Bf, OBf);
    xtrans_kernel<<<dim3(NN / 64, CC / 64, BB), 256, 0, stream>>>(x, Flag, xt);
    conv3_mfma_kernel<<<dim3(NN / 16, BB), 256, 0, stream>>>(xt, Wb, Bf, T1b, T2t, T3b);
    transpose_kernel<<<dim3(CHH / 64, NN / 64, BB), 256, 0, stream>>>(T3b, X3t, NN, CHH);
    stats_mfma_kernel<<<dim3(1024), 256, 0, stream>>>(T1b, T2t, Lpart);
    attn_mfma_kernel<<<dim3(512), 512, 0, stream>>>(T1b, T2t, X3t, Lpart, Yp0, Yp1, Yp2, Yp3);
    outconv_mfma_kernel<<<dim3(NN / 16, BB), 256, 0, stream>>>(x, Yp0, Yp1, Yp2, Yp3,
                                                               OWb, OBf, Flag, d_out);
}

// Round 6
// 196.242 us; speedup vs baseline: 1.3887x; 1.0608x over previous
//
#include <hip/hip_runtime.h>
#include <hip/hip_bf16.h>

#define BB 4
#define CC 256
#define CHH 128
#define NN 4096
#define KSHIFT 12.0f

typedef __attribute__((ext_vector_type(8))) short bf16x8;
typedef __attribute__((ext_vector_type(4))) float f32x4;

__device__ __forceinline__ float to_f(float v) { return v; }
__device__ __forceinline__ float to_f(__hip_bfloat16 v) { return __bfloat162float(v); }
__device__ __forceinline__ void st_f(float* p, float v) { *p = v; }
__device__ __forceinline__ void st_f(__hip_bfloat16* p, float v) { *p = __float2bfloat16(v); }
__device__ __forceinline__ unsigned short f2bf(float f) {
    __hip_bfloat16 h = __float2bfloat16(f);
    unsigned short u;
    __builtin_memcpy(&u, &h, 2);
    return u;
}
__device__ __forceinline__ bf16x8 ldb8(const unsigned short* p) { return *(const bf16x8*)p; }

// async global->LDS, 16 B per lane. LDS dest = wave-uniform base + lane*16.
__device__ __forceinline__ void gload_lds16(const unsigned short* g, unsigned short* l) {
    __builtin_amdgcn_global_load_lds(
        (const __attribute__((address_space(1))) unsigned int*)g,
        (__attribute__((address_space(3))) unsigned int*)l, 16, 0, 0);
}

// ---------------------------------------------------------------------------
// Inline wire-dtype detection (ROUND 17: detect_kernel deleted; each block
// that needs the flag recomputes it from the first 128 bf16 of tb — all L2
// hits, ~free). Semantics identical to the proven rounds-3-10 heuristic.
// ---------------------------------------------------------------------------
__device__ __forceinline__ int detect_flag_block(const void* tb, int* sflag) {
    int tid = threadIdx.x;
    if (tid < 64) {
        const __hip_bfloat16* p = (const __hip_bfloat16*)tb;
        int big = 0, zero_even = 0;
#pragma unroll
        for (int k = 0; k < 2; ++k) {
            int idx = tid * 2 + k;
            float v = __bfloat162float(p[idx]);
            if (!(fabsf(v) <= 0.5f)) big = 1;
            if ((idx & 1) == 0 && v == 0.0f) zero_even = 1;
        }
        unsigned long long bigm = __ballot(big);
        unsigned long long zm = __ballot(zero_even);
        if (tid == 0) *sflag = (bigm != 0ULL || __popcll(zm) >= 32) ? 1 : 0;
    }
    __syncthreads();
    return *sflag;
}

// ---------------------------------------------------------------------------
// Kernel A (ROUND 17): prep + xtrans fused — both depend only on inputs.
// Blocks 0..514: weight/bias conversion (proven round 6).
// Blocks 515..1538: xt[b][p][c] = bf16(x[b][c][p]) (proven round 6).
// ---------------------------------------------------------------------------
template <typename T>
__device__ __forceinline__ void prep_body(const T* tw, const T* fw, const T* gw, const T* ow,
                                          const T* tb2, const T* fb, const T* gb, const T* ob,
                                          unsigned short* Wb, unsigned short* OWb,
                                          float* Bf, float* OBf) {
    int idx = blockIdx.x * 256 + threadIdx.x;
    if (idx < 98304) {
        int cv = idx >> 15, rem = idx & 32767;
        const T* src = cv == 0 ? tw : (cv == 1 ? fw : gw);
        Wb[idx] = f2bf(to_f(src[rem]));
    } else if (idx < 131072) {
        OWb[idx - 98304] = f2bf(to_f(ow[idx - 98304]));
    } else if (idx < 131456) {
        int r = idx - 131072;
        int cv = r >> 7, j = r & 127;
        const T* src = cv == 0 ? tb2 : (cv == 1 ? fb : gb);
        Bf[r] = to_f(src[j]);
    } else if (idx < 131712) {
        OBf[idx - 131456] = to_f(ob[idx - 131456]);
    }
}

template <typename T>
__device__ __forceinline__ void xtrans_body(const T* __restrict__ x, unsigned short* __restrict__ xt,
                                            int id, unsigned short (*t)[68]) {
    int b = id >> 8;
    const T* in = x + (size_t)b * CC * NN;
    unsigned short* out = xt + (size_t)b * NN * CC;
    int p0 = (id & 63) * 64, c0 = ((id >> 6) & 3) * 64;
    int flat = threadIdx.x;
#pragma unroll
    for (int tt = 0; tt < 16; ++tt) {
        int idd = flat + tt * 256;
        int rr = idd >> 6, cc = idd & 63;
        t[cc][rr] = f2bf(to_f(in[(size_t)(c0 + rr) * NN + p0 + cc]));
    }
    __syncthreads();
#pragma unroll
    for (int tt = 0; tt < 16; ++tt) {
        int idd = flat + tt * 256;
        int pp = idd >> 6, jj = idd & 63;
        out[(size_t)(p0 + pp) * CC + c0 + jj] = t[pp][jj];
    }
}

__launch_bounds__(256)
__global__ void prep_xtrans_kernel(const void* x,
                                   const void* tw, const void* fw, const void* gw, const void* ow,
                                   const void* tb2, const void* fb, const void* gb, const void* ob,
                                   unsigned short* Wb, unsigned short* OWb,
                                   float* Bf, float* OBf,
                                   unsigned short* __restrict__ xt) {
    __shared__ int sflag;
    __shared__ unsigned short t[64][68];
    int flag = detect_flag_block(tb2, &sflag);
    if (blockIdx.x < 515) {
        if (flag)
            prep_body<float>((const float*)tw, (const float*)fw, (const float*)gw, (const float*)ow,
                             (const float*)tb2, (const float*)fb, (const float*)gb, (const float*)ob,
                             Wb, OWb, Bf, OBf);
        else
            prep_body<__hip_bfloat16>((const __hip_bfloat16*)tw, (const __hip_bfloat16*)fw,
                                      (const __hip_bfloat16*)gw, (const __hip_bfloat16*)ow,
                                      (const __hip_bfloat16*)tb2, (const __hip_bfloat16*)fb,
                                      (const __hip_bfloat16*)gb, (const __hip_bfloat16*)ob,
                                      Wb, OWb, Bf, OBf);
    } else {
        int id = blockIdx.x - 515;
        if (flag) xtrans_body<float>((const float*)x, xt, id, t);
        else      xtrans_body<__hip_bfloat16>((const __hip_bfloat16*)x, xt, id, t);
    }
}

// ---------------------------------------------------------------------------
// Kernel B: three 1x1 convs via MFMA (proven; see round-11 note on X3t).
// ---------------------------------------------------------------------------
__launch_bounds__(256)
__global__ void conv3_mfma_kernel(const unsigned short* __restrict__ xt,
                                  const unsigned short* __restrict__ Wb,
                                  const float* __restrict__ Bf,
                                  unsigned short* __restrict__ T1b,
                                  unsigned short* __restrict__ T2t,
                                  unsigned short* __restrict__ T3b) {
    int b = blockIdx.y;
    int p0 = blockIdx.x * 16;
    int flat = threadIdx.x;
    int w = flat >> 6, lane = flat & 63, m = lane & 15, quad = lane >> 4;
    const unsigned short* xrow = xt + ((size_t)b * NN + p0 + m) * CC;
    bf16x8 xf[8];
#pragma unroll
    for (int kc = 0; kc < 8; ++kc)
        xf[kc] = ldb8(&xrow[kc * 32 + quad * 8]);
    unsigned short* t1  = T1b + (size_t)b * CHH * NN;
    unsigned short* t2t = T2t + (size_t)b * CHH * NN;   // [p][o], row stride 128
    unsigned short* t3  = T3b + (size_t)b * CHH * NN;   // natural (CH,N)
#pragma unroll
    for (int q = 0; q < 6; ++q) {
        int t = w * 6 + q;
        int cv = t >> 3, ot = t & 7;
        int o0 = ot * 16;
        const unsigned short* wrow = Wb + ((size_t)cv * CHH + o0 + m) * CC;
        f32x4 acc = {0.f, 0.f, 0.f, 0.f};
#pragma unroll
        for (int kc = 0; kc < 8; ++kc) {
            bf16x8 wf = ldb8(&wrow[kc * 32 + quad * 8]);
            acc = __builtin_amdgcn_mfma_f32_16x16x32_bf16(wf, xf[kc], acc, 0, 0, 0);
        }
        unsigned short hv[4];
#pragma unroll
        for (int r = 0; r < 4; ++r)
            hv[r] = f2bf(acc[r] + Bf[cv * CHH + o0 + quad * 4 + r]);
        if (cv == 1) {
            unsigned int lo = (unsigned int)hv[0] | ((unsigned int)hv[1] << 16);
            unsigned int hi = (unsigned int)hv[2] | ((unsigned int)hv[3] << 16);
            int src = (lane & 3) * 16 + (lane >> 2);
            unsigned int tlo = (unsigned int)__shfl((int)lo, src, 64);
            unsigned int thi = (unsigned int)__shfl((int)hi, src, 64);
            unsigned int* dst = (unsigned int*)&t2t[(size_t)(p0 + (lane >> 2)) * CHH +
                                                    o0 + (lane & 3) * 4];
            dst[0] = tlo;
            dst[1] = thi;
        } else {
            unsigned short* outp = (cv == 0) ? t1 : t3;
#pragma unroll
            for (int r = 0; r < 4; ++r)
                outp[(size_t)(o0 + quad * 4 + r) * NN + p0 + m] = hv[r];
        }
    }
}

// ---------------------------------------------------------------------------
// Kernel C (ROUND 17): transpose + stats fused — mutually independent, both
// depend only on conv3 outputs. Blocks 0..1023: stats (dispatched first =
// long pole); blocks 1024..1535: X3t transpose (memory-bound, fills stats'
// CU bubbles). Transpose scratch aliases the stats LDS arena.
// ---------------------------------------------------------------------------
__launch_bounds__(256)
__global__ void trans_stats_kernel(const unsigned short* __restrict__ T1b,
                                   const unsigned short* __restrict__ T2t,
                                   const unsigned short* __restrict__ T3b,
                                   unsigned short* __restrict__ X3t,
                                   float* __restrict__ Lpart) {
    __shared__ unsigned short arena[2 * 64 * 128];   // 32 KB
    int flat = threadIdx.x;
    if (blockIdx.x >= 1024) {
        // ---- transpose part: X3t (NN x CHH view) <- T3b, 64x64 tiles ----
        int id = blockIdx.x - 1024;            // 0..511
        int bz = id >> 7;                      // batch
        int by = (id >> 1) & 63;               // row tile (NN)
        int bx = id & 1;                       // col tile (CHH)
        const unsigned short* in = T3b + (size_t)bz * NN * CHH;
        unsigned short* out = X3t + (size_t)bz * NN * CHH;
        int c0 = bx * 64, r0 = by * 64;
        unsigned short (*t)[68] = (unsigned short (*)[68])arena;
#pragma unroll
        for (int tt = 0; tt < 16; ++tt) {
            int id2 = flat + tt * 256;
            int r = id2 >> 6, c = id2 & 63;
            t[c][r] = in[(size_t)(r0 + r) * CHH + c0 + c];
        }
        __syncthreads();
#pragma unroll
        for (int tt = 0; tt < 16; ++tt) {
            int id2 = flat + tt * 256;
            int c = id2 >> 6, r = id2 & 63;
            out[(size_t)(c0 + c) * NN + r0 + r] = t[c][r];
        }
        return;
    }
    // ---- stats part: colsum exp(S-K), round-12 dbuf + single barrier ----
    int blk = blockIdx.x;
    int b = (blk & 7) >> 1;
    int rest = (blk >> 3) * 2 + (blk & 1);   // 0..255 = strip*8 + iq
    int strip = rest >> 3, iq = rest & 7;
    int ibase = iq * 512;
    int w = flat >> 6, lane = flat & 63, m = lane & 15, quad = lane >> 4;
    const unsigned short* A  = T1b + (size_t)b * CHH * NN;
    const unsigned short* Bt = T2t + (size_t)b * CHH * NN;

    int u0w = strip * 128 + w * 32;           // this wave's 32-u window
    bf16x8 bfr[2][4];
#pragma unroll
    for (int g = 0; g < 2; ++g)
#pragma unroll
        for (int kc = 0; kc < 4; ++kc)
            bfr[g][kc] = ldb8(&Bt[(size_t)(u0w + g * 16 + m) * CHH + kc * 32 + quad * 8]);

#define STAGE_TH(dst, ii)                                                          \
    _Pragma("unroll")                                                              \
    for (int i_ = 0; i_ < 4; ++i_) {                                               \
        int sl = i_ * 256 + flat;                                                  \
        int r_ = sl >> 4, ch_ = sl & 15;                                           \
        int c_ = ch_ ^ (r_ & 7);                                                   \
        gload_lds16(&A[(size_t)((ii) + r_) * CHH + c_ * 8],                        \
                    arena + (dst) * 8192 + sl * 8);                                \
    }

    float csum[2] = {0.f, 0.f};
    STAGE_TH(0, ibase);                      // prologue: tile 0
    __syncthreads();                         // tile 0 ready (vmcnt drained)
    int cur = 0;
    for (int t = 0; t < 8; ++t) {            // 8 i-tiles of 64 in this chunk
        if (t < 7) { STAGE_TH(cur ^ 1, ibase + (t + 1) * 64); }
        const unsigned short* thc = arena + cur * 8192;
#pragma unroll
        for (int s = 0; s < 4; ++s) {
            int irow = s * 16 + m;
            bf16x8 af[4];
#pragma unroll
            for (int kc = 0; kc < 4; ++kc) {
                int ch = (kc * 4 + quad) ^ (irow & 7);
                af[kc] = *(const bf16x8*)&thc[irow * 128 + ch * 8];
            }
#pragma unroll
            for (int g = 0; g < 2; ++g) {
                f32x4 acc = {0.f, 0.f, 0.f, 0.f};
#pragma unroll
                for (int kc = 0; kc < 4; ++kc)
                    acc = __builtin_amdgcn_mfma_f32_16x16x32_bf16(af[kc], bfr[g][kc], acc, 0, 0, 0);
#pragma unroll
                for (int r = 0; r < 4; ++r)
                    csum[g] += __expf(acc[r] - KSHIFT);
            }
        }
        if (t < 7) {
            __syncthreads();                 // publishes tile t+1, protects buf t
            cur ^= 1;
        }
    }
#undef STAGE_TH
#pragma unroll
    for (int g = 0; g < 2; ++g) {
        csum[g] += __shfl_xor(csum[g], 16, 64);
        csum[g] += __shfl_xor(csum[g], 32, 64);
        if (lane < 16)
            Lpart[((size_t)iq * BB + b) * NN + u0w + g * 16 + m] = csum[g];
    }
}

// ---------------------------------------------------------------------------
// Kernel D (pass B): Y = P @ X3. ROUND 17: exact revert to the round-15
// structure (48.6 us, VGPR 60, 34% occupancy): 8 waves = 4 i-groups
// (32 rows) x 2 j-halves. Round-16's (2,4) partition regressed: unified
// VGPR+AGPR footprint > 128/wave halved blocks/CU (occupancy 34->19%).
// ---------------------------------------------------------------------------
__launch_bounds__(512, 2)
__global__ void attn_mfma_kernel(const unsigned short* __restrict__ T1b,
                                 const unsigned short* __restrict__ T2t,
                                 const unsigned short* __restrict__ X3t,
                                 const float* __restrict__ Lpart,
                                 unsigned short* __restrict__ Yp0,
                                 unsigned short* __restrict__ Yp1,
                                 unsigned short* __restrict__ Yp2,
                                 unsigned short* __restrict__ Yp3) {
    int blk = blockIdx.x;
    int b = (blk & 7) >> 1;
    int rest = (blk >> 3) * 2 + (blk & 1);   // 0..127 = it*4 + uc
    int it = rest >> 2, uc = rest & 3;
    int i0 = it * 128;
    unsigned short* Yp = uc == 0 ? Yp0 : (uc == 1 ? Yp1 : (uc == 2 ? Yp2 : Yp3));
    int flat = threadIdx.x;                   // 0..511
    int w = flat >> 6, lane = flat & 63, m = lane & 15, quad = lane >> 4;
    int ig = w & 3, h = w >> 2;               // i-group (32 rows), j-half/u-half
    const unsigned short* A  = T1b + (size_t)b * CHH * NN;
    const unsigned short* Bt = T2t + (size_t)b * CHH * NN;
    const unsigned short* X3 = X3t + (size_t)b * CHH * NN;

    // LDS arena, 69,632 B:
    //   [     0, 32768) bt   : phi^T tile, swizzled, dbuf 2 x 64x128 bf16
    //   [ 32768, 49152) x3   : X3 tile, swizzled, single 128x64 bf16
    //   [ 49152, 65536) pT   : per-ig P tiles [4][32 rows][64] bf16, XOR-swz
    //   [ 65536, 69632) llh  : 1024 f32 LL values
    __shared__ __align__(16) unsigned char smem[69632];
    unsigned short* bt0 = (unsigned short*)smem;
    unsigned short* x3s = (unsigned short*)(smem + 32768);
    unsigned short* pTg = (unsigned short*)(smem + 49152) + ig * 2048; // [32][64]
    float* llh = (float*)(smem + 65536);

    int ubeg = uc * 1024;
#pragma unroll
    for (int k = 0; k < 2; ++k) {             // LL prologue
        int idx = k * 512 + flat;
        int u = ubeg + idx;
        float s = 0.f;
#pragma unroll
        for (int c = 0; c < 8; ++c)
            s += Lpart[((size_t)c * BB + b) * NN + u];
        llh[idx] = logf(s) + KSHIFT;
    }

    int iw = i0 + ig * 32;                    // this wave's 32 i-rows
    int j0 = h * 64;                          // this wave's 64 j-cols
    bf16x8 ath[2][4];
#pragma unroll
    for (int g = 0; g < 2; ++g)
#pragma unroll
        for (int kc = 0; kc < 4; ++kc)
            ath[g][kc] = ldb8(&A[(size_t)(iw + g * 16 + m) * CHH + kc * 32 + quad * 8]);
    f32x4 yacc[2][4];
#pragma unroll
    for (int g = 0; g < 2; ++g)
#pragma unroll
        for (int js = 0; js < 4; ++js) yacc[g][js] = (f32x4){0.f, 0.f, 0.f, 0.f};

#define STAGE_BT(dst, uu)                                                          \
    _Pragma("unroll")                                                              \
    for (int i_ = 0; i_ < 2; ++i_) {          /* 16 KB */                          \
        int sl = i_ * 512 + flat;                                                  \
        int u_ = sl >> 4, ch_ = sl & 15;                                           \
        int c_ = ch_ ^ (u_ & 7);                                                   \
        gload_lds16(&Bt[(size_t)((uu) + u_) * CHH + c_ * 8],                       \
                    bt0 + (dst) * 8192 + sl * 8);                                  \
    }
#define STAGE_X3(uu)                                                               \
    _Pragma("unroll")                                                              \
    for (int i_ = 0; i_ < 2; ++i_) {          /* 16 KB */                          \
        int sl = i_ * 512 + flat;                                                  \
        int j_ = sl >> 3, ch_ = sl & 7;                                            \
        int c_ = ch_ ^ (j_ & 7);                                                   \
        gload_lds16(&X3[(size_t)j_ * NN + (uu) + c_ * 8], x3s + sl * 8);           \
    }

    STAGE_BT(0, ubeg);                        // prologue: bt tile 0 + x3 tile 0
    STAGE_X3(ubeg);
    __syncthreads();                          // staging drained + llh visible
    int cur = 0;
    for (int t = 0; t < 16; ++t) {
        int u0 = ubeg + t * 64;
        if (t < 15) { STAGE_BT(cur ^ 1, u0 + 64); }   // drains at barrier A
        const unsigned short* btc = bt0 + cur * 8192;
        // ---- S phase: S(32i x 32u-half h), exp, P -> shared swizzled pT ----
#pragma unroll
        for (int su = 0; su < 2; ++su) {
            int ul = h * 32 + su * 16 + m;    // u within tile (this wave's half)
            f32x4 a0 = {0.f, 0.f, 0.f, 0.f}, a1 = {0.f, 0.f, 0.f, 0.f};
#pragma unroll
            for (int kc = 0; kc < 4; ++kc) {
                int ch = (kc * 4 + quad) ^ (ul & 7);
                bf16x8 bf = *(const bf16x8*)&btc[ul * 128 + ch * 8];
                a0 = __builtin_amdgcn_mfma_f32_16x16x32_bf16(ath[0][kc], bf, a0, 0, 0, 0);
                a1 = __builtin_amdgcn_mfma_f32_16x16x32_bf16(ath[1][kc], bf, a1, 0, 0, 0);
            }
            float ll = llh[u0 - ubeg + ul];
#pragma unroll
            for (int r = 0; r < 4; ++r) {
                int r0 = quad * 4 + r;        // local row for g=0; g=1 adds 16
                pTg[r0 * 64 + ((ul >> 3) ^ (r0 & 7)) * 8 + (ul & 7)] =
                    f2bf(__expf(a0[r] - ll));
                pTg[(16 + r0) * 64 + ((ul >> 3) ^ (r0 & 7)) * 8 + (ul & 7)] =
                    f2bf(__expf(a1[r] - ll));
            }
        }
        __syncthreads();                      // A: pT published; x3(t)+bt(t+1) drained
        // ---- PV phase: Y(32i x 64j, cols j0..j0+63) over full 64-u K ----
#pragma unroll
        for (int ku = 0; ku < 2; ++ku) {
            bf16x8 pa0 = *(const bf16x8*)&pTg[m * 64 + ((ku * 4 + quad) ^ (m & 7)) * 8];
            bf16x8 pa1 = *(const bf16x8*)&pTg[(16 + m) * 64 + ((ku * 4 + quad) ^ (m & 7)) * 8];
#pragma unroll
            for (int js = 0; js < 4; ++js) {
                int j = j0 + js * 16 + m;
                int ch = (ku * 4 + quad) ^ (j & 7);
                bf16x8 xb = *(const bf16x8*)&x3s[j * 64 + ch * 8];
                yacc[0][js] = __builtin_amdgcn_mfma_f32_16x16x32_bf16(pa0, xb, yacc[0][js], 0, 0, 0);
                yacc[1][js] = __builtin_amdgcn_mfma_f32_16x16x32_bf16(pa1, xb, yacc[1][js], 0, 0, 0);
            }
        }
        __syncthreads();                      // B: pT + x3 reads done
        if (t < 15) { STAGE_X3(u0 + 64); }    // drains at A(t+1), under S(t+1)
        cur ^= 1;
    }
#undef STAGE_BT
#undef STAGE_X3
#pragma unroll
    for (int g = 0; g < 2; ++g)
#pragma unroll
        for (int js = 0; js < 4; ++js)
#pragma unroll
            for (int r = 0; r < 4; ++r)
                Yp[((size_t)b * NN + iw + g * 16 + quad * 4 + r) * CHH +
                   j0 + js * 16 + m] = f2bf(yacc[g][js][r]);
}

// ---------------------------------------------------------------------------
// Kernel E: out = x + out_w @ (Yp0+Yp1+Yp2+Yp3)^T + out_b via MFMA
// (proven round 10; ROUND 17: flag computed inline).
// ---------------------------------------------------------------------------
template <typename T>
__device__ __forceinline__ void outconv_body(const T* __restrict__ x,
                                             const unsigned short* __restrict__ Yp0,
                                             const unsigned short* __restrict__ Yp1,
                                             const unsigned short* __restrict__ Yp2,
                                             const unsigned short* __restrict__ Yp3,
                                             const unsigned short* __restrict__ OWb,
                                             const float* __restrict__ OBf,
                                             T* __restrict__ out) {
    int b = blockIdx.y;
    int p0 = blockIdx.x * 16;
    int flat = threadIdx.x;
    int w = flat >> 6, lane = flat & 63, m = lane & 15, quad = lane >> 4;
    size_t yoff = ((size_t)b * NN + p0 + m) * CHH;
    const unsigned short* yrows[4] = {Yp0 + yoff, Yp1 + yoff, Yp2 + yoff, Yp3 + yoff};
    bf16x8 yf[4][4];
#pragma unroll
    for (int pz = 0; pz < 4; ++pz)
#pragma unroll
        for (int kc = 0; kc < 4; ++kc)
            yf[pz][kc] = ldb8(&yrows[pz][kc * 32 + quad * 8]);
#pragma unroll
    for (int q = 0; q < 4; ++q) {
        int o0 = (w * 4 + q) * 16;
        const unsigned short* wrow = OWb + (size_t)(o0 + m) * CHH;
        f32x4 acc = {0.f, 0.f, 0.f, 0.f};
#pragma unroll
        for (int kc = 0; kc < 4; ++kc) {
            bf16x8 aw = ldb8(&wrow[kc * 32 + quad * 8]);
#pragma unroll
            for (int pz = 0; pz < 4; ++pz)
                acc = __builtin_amdgcn_mfma_f32_16x16x32_bf16(aw, yf[pz][kc], acc, 0, 0, 0);
        }
#pragma unroll
        for (int r = 0; r < 4; ++r) {
            int co = o0 + quad * 4 + r;
            size_t oi = ((size_t)b * CC + co) * NN + p0 + m;
            st_f(&out[oi], acc[r] + OBf[co] + to_f(x[oi]));
        }
    }
}

__launch_bounds__(256)
__global__ void outconv_mfma_kernel(const void* x, const void* tb2,
                                    const unsigned short* __restrict__ Yp0,
                                    const unsigned short* __restrict__ Yp1,
                                    const unsigned short* __restrict__ Yp2,
                                    const unsigned short* __restrict__ Yp3,
                                    const unsigned short* __restrict__ OWb,
                                    const float* __restrict__ OBf,
                                    void* out) {
    __shared__ int sflag;
    int flag = detect_flag_block(tb2, &sflag);
    if (flag)
        outconv_body<float>((const float*)x, Yp0, Yp1, Yp2, Yp3, OWb, OBf, (float*)out);
    else
        outconv_body<__hip_bfloat16>((const __hip_bfloat16*)x, Yp0, Yp1, Yp2, Yp3, OWb, OBf,
                                     (__hip_bfloat16*)out);
}

extern "C" void kernel_launch(void* const* d_in, const int* in_sizes, int n_in,
                              void* d_out, int out_size, void* d_ws, size_t ws_size,
                              hipStream_t stream) {
    const void* x  = d_in[0];
    const void* tw = d_in[1];
    const void* tb = d_in[2];
    const void* fw = d_in[3];
    const void* fb = d_in[4];
    const void* gw = d_in[5];
    const void* gb = d_in[6];
    const void* ow = d_in[7];
    const void* ob = d_in[8];

    // Workspace (~30 MB): conv3 writes T1b natural, T2t fused-transposed,
    // T3b natural; transpose T3b -> X3t. Aliases: Yp0/Yp1 <- xt (dead after
    // conv3), Yp2 <- T3b (dead after the X3t transpose), Yp3 fresh.
    const size_t TE = (size_t)BB * CHH * NN;        // 2,097,152
    unsigned short* T1b = (unsigned short*)d_ws;
    unsigned short* T2t = T1b + TE;                 // phi transposed [p][o]
    unsigned short* X3t = T2t + TE;                 // g-view transposed [j][u]
    unsigned short* T3b = X3t + TE;                 // g natural (CH,N)
    unsigned short* xt  = T3b + TE;                 // 2*TE shorts (dead after conv3)
    unsigned short* Yp0 = xt;                       // alias
    unsigned short* Yp1 = xt + TE;                  // alias
    unsigned short* Yp2 = T3b;                      // alias (dead after transpose)
    unsigned short* Yp3 = xt + 2 * TE;              // fresh
    unsigned short* Wb  = Yp3 + TE;                 // 98304 shorts
    unsigned short* OWb = Wb + 98304;               // 32768 shorts
    float* Bf    = (float*)(OWb + 32768);           // 384
    float* OBf   = Bf + 384;                        // 256
    float* Lpart = OBf + 256;                       // 8 * BB * NN = 131072

    prep_xtrans_kernel<<<dim3(1539), 256, 0, stream>>>(x, tw, fw, gw, ow, tb, fb, gb, ob,
                                                       Wb, OWb, Bf, OBf, xt);
    conv3_mfma_kernel<<<dim3(NN / 16, BB), 256, 0, stream>>>(xt, Wb, Bf, T1b, T2t, T3b);
    trans_stats_kernel<<<dim3(1536), 256, 0, stream>>>(T1b, T2t, T3b, X3t, Lpart);
    attn_mfma_kernel<<<dim3(512), 512, 0, stream>>>(T1b, T2t, X3t, Lpart, Yp0, Yp1, Yp2, Yp3);
    outconv_mfma_kernel<<<dim3(NN / 16, BB), 256, 0, stream>>>(x, tb, Yp0, Yp1, Yp2, Yp3,
                                                               OWb, OBf, d_out);
}

// Round 8
// 192.271 us; speedup vs baseline: 1.4174x; 1.0207x over previous
//
#include <hip/hip_runtime.h>
#include <hip/hip_bf16.h>

#define BB 4
#define CC 256
#define CHH 128
#define NN 4096
#define KSHIFT 12.0f

typedef __attribute__((ext_vector_type(8))) short bf16x8;
typedef __attribute__((ext_vector_type(4))) float f32x4;

__device__ __forceinline__ float to_f(float v) { return v; }
__device__ __forceinline__ float to_f(__hip_bfloat16 v) { return __bfloat162float(v); }
__device__ __forceinline__ void st_f(float* p, float v) { *p = v; }
__device__ __forceinline__ void st_f(__hip_bfloat16* p, float v) { *p = __float2bfloat16(v); }
__device__ __forceinline__ unsigned short f2bf(float f) {
    __hip_bfloat16 h = __float2bfloat16(f);
    unsigned short u;
    __builtin_memcpy(&u, &h, 2);
    return u;
}
__device__ __forceinline__ bf16x8 ldb8(const unsigned short* p) { return *(const bf16x8*)p; }

// async global->LDS, 16 B per lane. LDS dest = wave-uniform base + lane*16.
__device__ __forceinline__ void gload_lds16(const unsigned short* g, unsigned short* l) {
    __builtin_amdgcn_global_load_lds(
        (const __attribute__((address_space(1))) unsigned int*)g,
        (__attribute__((address_space(3))) unsigned int*)l, 16, 0, 0);
}

// ---------------------------------------------------------------------------
// Inline wire-dtype detection (proven heuristic, rounds 3-10).
// ROUND 19 note: the round-18 cooperative mega-kernel failed silently
// (hipLaunchCooperativeKernel is not graph-capturable on this harness —
// output stayed memset-0, absmax == max|ref|). Reverted to the proven
// round-17 five-dispatch structure; additions this round are T5 setprio
// around MFMA clusters + __logf only.
// ---------------------------------------------------------------------------
__device__ __forceinline__ int detect_flag_block(const void* tb, int* sflag) {
    int tid = threadIdx.x;
    if (tid < 64) {
        const __hip_bfloat16* p = (const __hip_bfloat16*)tb;
        int big = 0, zero_even = 0;
#pragma unroll
        for (int k = 0; k < 2; ++k) {
            int idx = tid * 2 + k;
            float v = __bfloat162float(p[idx]);
            if (!(fabsf(v) <= 0.5f)) big = 1;
            if ((idx & 1) == 0 && v == 0.0f) zero_even = 1;
        }
        unsigned long long bigm = __ballot(big);
        unsigned long long zm = __ballot(zero_even);
        if (tid == 0) *sflag = (bigm != 0ULL || __popcll(zm) >= 32) ? 1 : 0;
    }
    __syncthreads();
    return *sflag;
}

// ---------------------------------------------------------------------------
// Kernel A: prep + xtrans fused (proven round 17).
// Blocks 0..514: weight/bias conversion. Blocks 515..1538: x transpose.
// ---------------------------------------------------------------------------
template <typename T>
__device__ __forceinline__ void prep_body(const T* tw, const T* fw, const T* gw, const T* ow,
                                          const T* tb2, const T* fb, const T* gb, const T* ob,
                                          unsigned short* Wb, unsigned short* OWb,
                                          float* Bf, float* OBf) {
    int idx = blockIdx.x * 256 + threadIdx.x;
    if (idx < 98304) {
        int cv = idx >> 15, rem = idx & 32767;
        const T* src = cv == 0 ? tw : (cv == 1 ? fw : gw);
        Wb[idx] = f2bf(to_f(src[rem]));
    } else if (idx < 131072) {
        OWb[idx - 98304] = f2bf(to_f(ow[idx - 98304]));
    } else if (idx < 131456) {
        int r = idx - 131072;
        int cv = r >> 7, j = r & 127;
        const T* src = cv == 0 ? tb2 : (cv == 1 ? fb : gb);
        Bf[r] = to_f(src[j]);
    } else if (idx < 131712) {
        OBf[idx - 131456] = to_f(ob[idx - 131456]);
    }
}

template <typename T>
__device__ __forceinline__ void xtrans_body(const T* __restrict__ x, unsigned short* __restrict__ xt,
                                            int id, unsigned short (*t)[68]) {
    int b = id >> 8;
    const T* in = x + (size_t)b * CC * NN;
    unsigned short* out = xt + (size_t)b * NN * CC;
    int p0 = (id & 63) * 64, c0 = ((id >> 6) & 3) * 64;
    int flat = threadIdx.x;
#pragma unroll
    for (int tt = 0; tt < 16; ++tt) {
        int idd = flat + tt * 256;
        int rr = idd >> 6, cc = idd & 63;
        t[cc][rr] = f2bf(to_f(in[(size_t)(c0 + rr) * NN + p0 + cc]));
    }
    __syncthreads();
#pragma unroll
    for (int tt = 0; tt < 16; ++tt) {
        int idd = flat + tt * 256;
        int pp = idd >> 6, jj = idd & 63;
        out[(size_t)(p0 + pp) * CC + c0 + jj] = t[pp][jj];
    }
}

__launch_bounds__(256)
__global__ void prep_xtrans_kernel(const void* x,
                                   const void* tw, const void* fw, const void* gw, const void* ow,
                                   const void* tb2, const void* fb, const void* gb, const void* ob,
                                   unsigned short* Wb, unsigned short* OWb,
                                   float* Bf, float* OBf,
                                   unsigned short* __restrict__ xt) {
    __shared__ int sflag;
    __shared__ unsigned short t[64][68];
    int flag = detect_flag_block(tb2, &sflag);
    if (blockIdx.x < 515) {
        if (flag)
            prep_body<float>((const float*)tw, (const float*)fw, (const float*)gw, (const float*)ow,
                             (const float*)tb2, (const float*)fb, (const float*)gb, (const float*)ob,
                             Wb, OWb, Bf, OBf);
        else
            prep_body<__hip_bfloat16>((const __hip_bfloat16*)tw, (const __hip_bfloat16*)fw,
                                      (const __hip_bfloat16*)gw, (const __hip_bfloat16*)ow,
                                      (const __hip_bfloat16*)tb2, (const __hip_bfloat16*)fb,
                                      (const __hip_bfloat16*)gb, (const __hip_bfloat16*)ob,
                                      Wb, OWb, Bf, OBf);
    } else {
        int id = blockIdx.x - 515;
        if (flag) xtrans_body<float>((const float*)x, xt, id, t);
        else      xtrans_body<__hip_bfloat16>((const __hip_bfloat16*)x, xt, id, t);
    }
}

// ---------------------------------------------------------------------------
// Kernel B: three 1x1 convs via MFMA (proven; see round-11 note on X3t).
// ---------------------------------------------------------------------------
__launch_bounds__(256)
__global__ void conv3_mfma_kernel(const unsigned short* __restrict__ xt,
                                  const unsigned short* __restrict__ Wb,
                                  const float* __restrict__ Bf,
                                  unsigned short* __restrict__ T1b,
                                  unsigned short* __restrict__ T2t,
                                  unsigned short* __restrict__ T3b) {
    int b = blockIdx.y;
    int p0 = blockIdx.x * 16;
    int flat = threadIdx.x;
    int w = flat >> 6, lane = flat & 63, m = lane & 15, quad = lane >> 4;
    const unsigned short* xrow = xt + ((size_t)b * NN + p0 + m) * CC;
    bf16x8 xf[8];
#pragma unroll
    for (int kc = 0; kc < 8; ++kc)
        xf[kc] = ldb8(&xrow[kc * 32 + quad * 8]);
    unsigned short* t1  = T1b + (size_t)b * CHH * NN;
    unsigned short* t2t = T2t + (size_t)b * CHH * NN;   // [p][o], row stride 128
    unsigned short* t3  = T3b + (size_t)b * CHH * NN;   // natural (CH,N)
#pragma unroll
    for (int q = 0; q < 6; ++q) {
        int t = w * 6 + q;
        int cv = t >> 3, ot = t & 7;
        int o0 = ot * 16;
        const unsigned short* wrow = Wb + ((size_t)cv * CHH + o0 + m) * CC;
        f32x4 acc = {0.f, 0.f, 0.f, 0.f};
        __builtin_amdgcn_s_setprio(1);
#pragma unroll
        for (int kc = 0; kc < 8; ++kc) {
            bf16x8 wf = ldb8(&wrow[kc * 32 + quad * 8]);
            acc = __builtin_amdgcn_mfma_f32_16x16x32_bf16(wf, xf[kc], acc, 0, 0, 0);
        }
        __builtin_amdgcn_s_setprio(0);
        unsigned short hv[4];
#pragma unroll
        for (int r = 0; r < 4; ++r)
            hv[r] = f2bf(acc[r] + Bf[cv * CHH + o0 + quad * 4 + r]);
        if (cv == 1) {
            unsigned int lo = (unsigned int)hv[0] | ((unsigned int)hv[1] << 16);
            unsigned int hi = (unsigned int)hv[2] | ((unsigned int)hv[3] << 16);
            int src = (lane & 3) * 16 + (lane >> 2);
            unsigned int tlo = (unsigned int)__shfl((int)lo, src, 64);
            unsigned int thi = (unsigned int)__shfl((int)hi, src, 64);
            unsigned int* dst = (unsigned int*)&t2t[(size_t)(p0 + (lane >> 2)) * CHH +
                                                    o0 + (lane & 3) * 4];
            dst[0] = tlo;
            dst[1] = thi;
        } else {
            unsigned short* outp = (cv == 0) ? t1 : t3;
#pragma unroll
            for (int r = 0; r < 4; ++r)
                outp[(size_t)(o0 + quad * 4 + r) * NN + p0 + m] = hv[r];
        }
    }
}

// ---------------------------------------------------------------------------
// Kernel C: transpose + stats fused (proven round 17). Blocks 0..1023:
// stats (long pole, dispatched first); blocks 1024..1535: X3t transpose.
// ROUND 19: setprio around the stats MFMA cluster.
// ---------------------------------------------------------------------------
__launch_bounds__(256)
__global__ void trans_stats_kernel(const unsigned short* __restrict__ T1b,
                                   const unsigned short* __restrict__ T2t,
                                   const unsigned short* __restrict__ T3b,
                                   unsigned short* __restrict__ X3t,
                                   float* __restrict__ Lpart) {
    __shared__ unsigned short arena[2 * 64 * 128];   // 32 KB
    int flat = threadIdx.x;
    if (blockIdx.x >= 1024) {
        // ---- transpose part: X3t (NN x CHH view) <- T3b, 64x64 tiles ----
        int id = blockIdx.x - 1024;            // 0..511
        int bz = id >> 7;                      // batch
        int by = (id >> 1) & 63;               // row tile (NN)
        int bx = id & 1;                       // col tile (CHH)
        const unsigned short* in = T3b + (size_t)bz * NN * CHH;
        unsigned short* out = X3t + (size_t)bz * NN * CHH;
        int c0 = bx * 64, r0 = by * 64;
        unsigned short (*t)[68] = (unsigned short (*)[68])arena;
#pragma unroll
        for (int tt = 0; tt < 16; ++tt) {
            int id2 = flat + tt * 256;
            int r = id2 >> 6, c = id2 & 63;
            t[c][r] = in[(size_t)(r0 + r) * CHH + c0 + c];
        }
        __syncthreads();
#pragma unroll
        for (int tt = 0; tt < 16; ++tt) {
            int id2 = flat + tt * 256;
            int c = id2 >> 6, r = id2 & 63;
            out[(size_t)(c0 + c) * NN + r0 + r] = t[c][r];
        }
        return;
    }
    // ---- stats part: colsum exp(S-K), round-12 dbuf + single barrier ----
    int blk = blockIdx.x;
    int b = (blk & 7) >> 1;
    int rest = (blk >> 3) * 2 + (blk & 1);   // 0..255 = strip*8 + iq
    int strip = rest >> 3, iq = rest & 7;
    int ibase = iq * 512;
    int w = flat >> 6, lane = flat & 63, m = lane & 15, quad = lane >> 4;
    const unsigned short* A  = T1b + (size_t)b * CHH * NN;
    const unsigned short* Bt = T2t + (size_t)b * CHH * NN;

    int u0w = strip * 128 + w * 32;           // this wave's 32-u window
    bf16x8 bfr[2][4];
#pragma unroll
    for (int g = 0; g < 2; ++g)
#pragma unroll
        for (int kc = 0; kc < 4; ++kc)
            bfr[g][kc] = ldb8(&Bt[(size_t)(u0w + g * 16 + m) * CHH + kc * 32 + quad * 8]);

#define STAGE_TH(dst, ii)                                                          \
    _Pragma("unroll")                                                              \
    for (int i_ = 0; i_ < 4; ++i_) {                                               \
        int sl = i_ * 256 + flat;                                                  \
        int r_ = sl >> 4, ch_ = sl & 15;                                           \
        int c_ = ch_ ^ (r_ & 7);                                                   \
        gload_lds16(&A[(size_t)((ii) + r_) * CHH + c_ * 8],                        \
                    arena + (dst) * 8192 + sl * 8);                                \
    }

    float csum[2] = {0.f, 0.f};
    STAGE_TH(0, ibase);                      // prologue: tile 0
    __syncthreads();                         // tile 0 ready (vmcnt drained)
    int cur = 0;
    for (int t = 0; t < 8; ++t) {            // 8 i-tiles of 64 in this chunk
        if (t < 7) { STAGE_TH(cur ^ 1, ibase + (t + 1) * 64); }
        const unsigned short* thc = arena + cur * 8192;
#pragma unroll
        for (int s = 0; s < 4; ++s) {
            int irow = s * 16 + m;
            bf16x8 af[4];
#pragma unroll
            for (int kc = 0; kc < 4; ++kc) {
                int ch = (kc * 4 + quad) ^ (irow & 7);
                af[kc] = *(const bf16x8*)&thc[irow * 128 + ch * 8];
            }
            __builtin_amdgcn_s_setprio(1);
#pragma unroll
            for (int g = 0; g < 2; ++g) {
                f32x4 acc = {0.f, 0.f, 0.f, 0.f};
#pragma unroll
                for (int kc = 0; kc < 4; ++kc)
                    acc = __builtin_amdgcn_mfma_f32_16x16x32_bf16(af[kc], bfr[g][kc], acc, 0, 0, 0);
#pragma unroll
                for (int r = 0; r < 4; ++r)
                    csum[g] += __expf(acc[r] - KSHIFT);
            }
            __builtin_amdgcn_s_setprio(0);
        }
        if (t < 7) {
            __syncthreads();                 // publishes tile t+1, protects buf t
            cur ^= 1;
        }
    }
#undef STAGE_TH
#pragma unroll
    for (int g = 0; g < 2; ++g) {
        csum[g] += __shfl_xor(csum[g], 16, 64);
        csum[g] += __shfl_xor(csum[g], 32, 64);
        if (lane < 16)
            Lpart[((size_t)iq * BB + b) * NN + u0w + g * 16 + m] = csum[g];
    }
}

// ---------------------------------------------------------------------------
// Kernel D (pass B): Y = P @ X3 (round-15/17 structure, 48.6-49.4 us,
// VGPR 60, 33% occupancy). 8 waves = 4 i-groups (32 rows) x 2 j-halves.
// ROUND 19: setprio around S and PV MFMA clusters; __logf in llh prologue.
// ---------------------------------------------------------------------------
__launch_bounds__(512, 2)
__global__ void attn_mfma_kernel(const unsigned short* __restrict__ T1b,
                                 const unsigned short* __restrict__ T2t,
                                 const unsigned short* __restrict__ X3t,
                                 const float* __restrict__ Lpart,
                                 unsigned short* __restrict__ Yp0,
                                 unsigned short* __restrict__ Yp1,
                                 unsigned short* __restrict__ Yp2,
                                 unsigned short* __restrict__ Yp3) {
    int blk = blockIdx.x;
    int b = (blk & 7) >> 1;
    int rest = (blk >> 3) * 2 + (blk & 1);   // 0..127 = it*4 + uc
    int it = rest >> 2, uc = rest & 3;
    int i0 = it * 128;
    unsigned short* Yp = uc == 0 ? Yp0 : (uc == 1 ? Yp1 : (uc == 2 ? Yp2 : Yp3));
    int flat = threadIdx.x;                   // 0..511
    int w = flat >> 6, lane = flat & 63, m = lane & 15, quad = lane >> 4;
    int ig = w & 3, h = w >> 2;               // i-group (32 rows), j-half/u-half
    const unsigned short* A  = T1b + (size_t)b * CHH * NN;
    const unsigned short* Bt = T2t + (size_t)b * CHH * NN;
    const unsigned short* X3 = X3t + (size_t)b * CHH * NN;

    // LDS arena, 69,632 B:
    //   [     0, 32768) bt   : phi^T tile, swizzled, dbuf 2 x 64x128 bf16
    //   [ 32768, 49152) x3   : X3 tile, swizzled, single 128x64 bf16
    //   [ 49152, 65536) pT   : per-ig P tiles [4][32 rows][64] bf16, XOR-swz
    //   [ 65536, 69632) llh  : 1024 f32 LL values
    __shared__ __align__(16) unsigned char smem[69632];
    unsigned short* bt0 = (unsigned short*)smem;
    unsigned short* x3s = (unsigned short*)(smem + 32768);
    unsigned short* pTg = (unsigned short*)(smem + 49152) + ig * 2048; // [32][64]
    float* llh = (float*)(smem + 65536);

    int ubeg = uc * 1024;
#pragma unroll
    for (int k = 0; k < 2; ++k) {             // LL prologue
        int idx = k * 512 + flat;
        int u = ubeg + idx;
        float s = 0.f;
#pragma unroll
        for (int c = 0; c < 8; ++c)
            s += Lpart[((size_t)c * BB + b) * NN + u];
        llh[idx] = __logf(s) + KSHIFT;
    }

    int iw = i0 + ig * 32;                    // this wave's 32 i-rows
    int j0 = h * 64;                          // this wave's 64 j-cols
    bf16x8 ath[2][4];
#pragma unroll
    for (int g = 0; g < 2; ++g)
#pragma unroll
        for (int kc = 0; kc < 4; ++kc)
            ath[g][kc] = ldb8(&A[(size_t)(iw + g * 16 + m) * CHH + kc * 32 + quad * 8]);
    f32x4 yacc[2][4];
#pragma unroll
    for (int g = 0; g < 2; ++g)
#pragma unroll
        for (int js = 0; js < 4; ++js) yacc[g][js] = (f32x4){0.f, 0.f, 0.f, 0.f};

#define STAGE_BT(dst, uu)                                                          \
    _Pragma("unroll")                                                              \
    for (int i_ = 0; i_ < 2; ++i_) {          /* 16 KB */                          \
        int sl = i_ * 512 + flat;                                                  \
        int u_ = sl >> 4, ch_ = sl & 15;                                           \
        int c_ = ch_ ^ (u_ & 7);                                                   \
        gload_lds16(&Bt[(size_t)((uu) + u_) * CHH + c_ * 8],                       \
                    bt0 + (dst) * 8192 + sl * 8);                                  \
    }
#define STAGE_X3(uu)                                                               \
    _Pragma("unroll")                                                              \
    for (int i_ = 0; i_ < 2; ++i_) {          /* 16 KB */                          \
        int sl = i_ * 512 + flat;                                                  \
        int j_ = sl >> 3, ch_ = sl & 7;                                            \
        int c_ = ch_ ^ (j_ & 7);                                                   \
        gload_lds16(&X3[(size_t)j_ * NN + (uu) + c_ * 8], x3s + sl * 8);           \
    }

    STAGE_BT(0, ubeg);                        // prologue: bt tile 0 + x3 tile 0
    STAGE_X3(ubeg);
    __syncthreads();                          // staging drained + llh visible
    int cur = 0;
    for (int t = 0; t < 16; ++t) {
        int u0 = ubeg + t * 64;
        if (t < 15) { STAGE_BT(cur ^ 1, u0 + 64); }   // drains at barrier A
        const unsigned short* btc = bt0 + cur * 8192;
        // ---- S phase: S(32i x 32u-half h), exp, P -> shared swizzled pT ----
#pragma unroll
        for (int su = 0; su < 2; ++su) {
            int ul = h * 32 + su * 16 + m;    // u within tile (this wave's half)
            f32x4 a0 = {0.f, 0.f, 0.f, 0.f}, a1 = {0.f, 0.f, 0.f, 0.f};
            __builtin_amdgcn_s_setprio(1);
#pragma unroll
            for (int kc = 0; kc < 4; ++kc) {
                int ch = (kc * 4 + quad) ^ (ul & 7);
                bf16x8 bf = *(const bf16x8*)&btc[ul * 128 + ch * 8];
                a0 = __builtin_amdgcn_mfma_f32_16x16x32_bf16(ath[0][kc], bf, a0, 0, 0, 0);
                a1 = __builtin_amdgcn_mfma_f32_16x16x32_bf16(ath[1][kc], bf, a1, 0, 0, 0);
            }
            __builtin_amdgcn_s_setprio(0);
            float ll = llh[u0 - ubeg + ul];
#pragma unroll
            for (int r = 0; r < 4; ++r) {
                int r0 = quad * 4 + r;        // local row for g=0; g=1 adds 16
                pTg[r0 * 64 + ((ul >> 3) ^ (r0 & 7)) * 8 + (ul & 7)] =
                    f2bf(__expf(a0[r] - ll));
                pTg[(16 + r0) * 64 + ((ul >> 3) ^ (r0 & 7)) * 8 + (ul & 7)] =
                    f2bf(__expf(a1[r] - ll));
            }
        }
        __syncthreads();                      // A: pT published; x3(t)+bt(t+1) drained
        // ---- PV phase: Y(32i x 64j, cols j0..j0+63) over full 64-u K ----
#pragma unroll
        for (int ku = 0; ku < 2; ++ku) {
            bf16x8 pa0 = *(const bf16x8*)&pTg[m * 64 + ((ku * 4 + quad) ^ (m & 7)) * 8];
            bf16x8 pa1 = *(const bf16x8*)&pTg[(16 + m) * 64 + ((ku * 4 + quad) ^ (m & 7)) * 8];
            __builtin_amdgcn_s_setprio(1);
#pragma unroll
            for (int js = 0; js < 4; ++js) {
                int j = j0 + js * 16 + m;
                int ch = (ku * 4 + quad) ^ (j & 7);
                bf16x8 xb = *(const bf16x8*)&x3s[j * 64 + ch * 8];
                yacc[0][js] = __builtin_amdgcn_mfma_f32_16x16x32_bf16(pa0, xb, yacc[0][js], 0, 0, 0);
                yacc[1][js] = __builtin_amdgcn_mfma_f32_16x16x32_bf16(pa1, xb, yacc[1][js], 0, 0, 0);
            }
            __builtin_amdgcn_s_setprio(0);
        }
        __syncthreads();                      // B: pT + x3 reads done
        if (t < 15) { STAGE_X3(u0 + 64); }    // drains at A(t+1), under S(t+1)
        cur ^= 1;
    }
#undef STAGE_BT
#undef STAGE_X3
#pragma unroll
    for (int g = 0; g < 2; ++g)
#pragma unroll
        for (int js = 0; js < 4; ++js)
#pragma unroll
            for (int r = 0; r < 4; ++r)
                Yp[((size_t)b * NN + iw + g * 16 + quad * 4 + r) * CHH +
                   j0 + js * 16 + m] = f2bf(yacc[g][js][r]);
}

// ---------------------------------------------------------------------------
// Kernel E: out = x + out_w @ (Yp0+Yp1+Yp2+Yp3)^T + out_b via MFMA
// (proven round 10; flag computed inline since round 17).
// ---------------------------------------------------------------------------
template <typename T>
__device__ __forceinline__ void outconv_body(const T* __restrict__ x,
                                             const unsigned short* __restrict__ Yp0,
                                             const unsigned short* __restrict__ Yp1,
                                             const unsigned short* __restrict__ Yp2,
                                             const unsigned short* __restrict__ Yp3,
                                             const unsigned short* __restrict__ OWb,
                                             const float* __restrict__ OBf,
                                             T* __restrict__ out) {
    int b = blockIdx.y;
    int p0 = blockIdx.x * 16;
    int flat = threadIdx.x;
    int w = flat >> 6, lane = flat & 63, m = lane & 15, quad = lane >> 4;
    size_t yoff = ((size_t)b * NN + p0 + m) * CHH;
    const unsigned short* yrows[4] = {Yp0 + yoff, Yp1 + yoff, Yp2 + yoff, Yp3 + yoff};
    bf16x8 yf[4][4];
#pragma unroll
    for (int pz = 0; pz < 4; ++pz)
#pragma unroll
        for (int kc = 0; kc < 4; ++kc)
            yf[pz][kc] = ldb8(&yrows[pz][kc * 32 + quad * 8]);
#pragma unroll
    for (int q = 0; q < 4; ++q) {
        int o0 = (w * 4 + q) * 16;
        const unsigned short* wrow = OWb + (size_t)(o0 + m) * CHH;
        f32x4 acc = {0.f, 0.f, 0.f, 0.f};
        __builtin_amdgcn_s_setprio(1);
#pragma unroll
        for (int kc = 0; kc < 4; ++kc) {
            bf16x8 aw = ldb8(&wrow[kc * 32 + quad * 8]);
#pragma unroll
            for (int pz = 0; pz < 4; ++pz)
                acc = __builtin_amdgcn_mfma_f32_16x16x32_bf16(aw, yf[pz][kc], acc, 0, 0, 0);
        }
        __builtin_amdgcn_s_setprio(0);
#pragma unroll
        for (int r = 0; r < 4; ++r) {
            int co = o0 + quad * 4 + r;
            size_t oi = ((size_t)b * CC + co) * NN + p0 + m;
            st_f(&out[oi], acc[r] + OBf[co] + to_f(x[oi]));
        }
    }
}

__launch_bounds__(256)
__global__ void outconv_mfma_kernel(const void* x, const void* tb2,
                                    const unsigned short* __restrict__ Yp0,
                                    const unsigned short* __restrict__ Yp1,
                                    const unsigned short* __restrict__ Yp2,
                                    const unsigned short* __restrict__ Yp3,
                                    const unsigned short* __restrict__ OWb,
                                    const float* __restrict__ OBf,
                                    void* out) {
    __shared__ int sflag;
    int flag = detect_flag_block(tb2, &sflag);
    if (flag)
        outconv_body<float>((const float*)x, Yp0, Yp1, Yp2, Yp3, OWb, OBf, (float*)out);
    else
        outconv_body<__hip_bfloat16>((const __hip_bfloat16*)x, Yp0, Yp1, Yp2, Yp3, OWb, OBf,
                                     (__hip_bfloat16*)out);
}

extern "C" void kernel_launch(void* const* d_in, const int* in_sizes, int n_in,
                              void* d_out, int out_size, void* d_ws, size_t ws_size,
                              hipStream_t stream) {
    const void* x  = d_in[0];
    const void* tw = d_in[1];
    const void* tb = d_in[2];
    const void* fw = d_in[3];
    const void* fb = d_in[4];
    const void* gw = d_in[5];
    const void* gb = d_in[6];
    const void* ow = d_in[7];
    const void* ob = d_in[8];

    // Workspace (~30 MB): conv3 writes T1b natural, T2t fused-transposed,
    // T3b natural; transpose T3b -> X3t. Aliases: Yp0/Yp1 <- xt (dead after
    // conv3), Yp2 <- T3b (dead after the X3t transpose), Yp3 fresh.
    const size_t TE = (size_t)BB * CHH * NN;        // 2,097,152
    unsigned short* T1b = (unsigned short*)d_ws;
    unsigned short* T2t = T1b + TE;                 // phi transposed [p][o]
    unsigned short* X3t = T2t + TE;                 // g-view transposed [j][u]
    unsigned short* T3b = X3t + TE;                 // g natural (CH,N)
    unsigned short* xt  = T3b + TE;                 // 2*TE shorts (dead after conv3)
    unsigned short* Yp0 = xt;                       // alias
    unsigned short* Yp1 = xt + TE;                  // alias
    unsigned short* Yp2 = T3b;                      // alias (dead after transpose)
    unsigned short* Yp3 = xt + 2 * TE;              // fresh
    unsigned short* Wb  = Yp3 + TE;                 // 98304 shorts
    unsigned short* OWb = Wb + 98304;               // 32768 shorts
    float* Bf    = (float*)(OWb + 32768);           // 384
    float* OBf   = Bf + 384;                        // 256
    float* Lpart = OBf + 256;                       // 8 * BB * NN = 131072

    prep_xtrans_kernel<<<dim3(1539), 256, 0, stream>>>(x, tw, fw, gw, ow, tb, fb, gb, ob,
                                                       Wb, OWb, Bf, OBf, xt);
    conv3_mfma_kernel<<<dim3(NN / 16, BB), 256, 0, stream>>>(xt, Wb, Bf, T1b, T2t, T3b);
    trans_stats_kernel<<<dim3(1536), 256, 0, stream>>>(T1b, T2t, T3b, X3t, Lpart);
    attn_mfma_kernel<<<dim3(512), 512, 0, stream>>>(T1b, T2t, X3t, Lpart, Yp0, Yp1, Yp2, Yp3);
    outconv_mfma_kernel<<<dim3(NN / 16, BB), 256, 0, stream>>>(x, tb, Yp0, Yp1, Yp2, Yp3,
                                                               OWb, OBf, d_out);
}